// Round 12
// baseline (802.879 us; speedup 1.0000x reference)
//
#include <hip/hip_runtime.h>
#include <math.h>

#define N_NODES 100000
#define E_EDGES 1600000
#define S_SNAP  4
#define D_IN    128
#define H_DIM   256
#define P_POST  10000
#define N4 (S_SNAP * N_NODES)               // 400000
#define E4 (S_SNAP * E_EDGES)               // 6400000

// ---- counting-sort graph prep ----
#define NBKT 128                             // coarse dst buckets per snapshot
#define BW_BKT 782                           // 128*782 = 100096 >= N_NODES
#define CHK 4096                             // edges per partition block
#define KPT (CHK / 256)                      // 16 edges per thread
#define NCHK ((E_EDGES + CHK - 1) / CHK)     // 391 chunks per snapshot
#define NPB (S_SNAP * NBKT)                  // 512 (snapshot,bucket) units
#define CSR_CAP 14336                        // LDS staging cap (mean 12500, 6sigma=13166)
#define PADCAP 5480                          // per-bucket pad slack: 7*782=5474 worst +align
#define CSRSZ (E4 + NPB * PADCAP + 8)        // 9,205,768 < 2^24

// ---- merged prep kernel block ranges: xb cast | w cast | pad-zero | count ----
#define CAST_XBLK (N_NODES * D_IN / 4 / 256)                  // 12500
#define CAST_WBLK ((D_IN * H_DIM + H_DIM * H_DIM) / 256)      // 384
#define PREP_CNT0 (CAST_XBLK + CAST_WBLK + 1)
#define PREP_GRID (PREP_CNT0 + S_SNAP * NCHK)                 // +1564 count blocks

#define GH_MTILES ((N_NODES + 63) / 64)      // 1563 full-row gemm_h blocks

typedef __attribute__((ext_vector_type(8))) short bf16x8;   // MFMA A/B frag (4 VGPRs)
typedef __attribute__((ext_vector_type(4))) float f32x4;    // MFMA C/D frag

// ---------- bf16 helpers ----------
__device__ __forceinline__ float bf2f(unsigned short u) {
    union { unsigned int i; float f; } v; v.i = ((unsigned int)u) << 16; return v.f;
}
__device__ __forceinline__ unsigned short f2bf(float f) {
    union { float f; unsigned int i; } v; v.f = f;
    unsigned int lsb = (v.i >> 16) & 1u;
    v.i += 0x7fffu + lsb;                 // round-nearest-even
    return (unsigned short)(v.i >> 16);
}

// ---- merged prep: X cast + W transpose-cast + pad-row zero + coarse histogram ----
__global__ __launch_bounds__(256) void prep_kernel(const float* __restrict__ x,
        const float* __restrict__ W1, const float* __restrict__ W2,
        const int* __restrict__ ei,
        unsigned short* __restrict__ xb, unsigned short* __restrict__ w1t,
        unsigned short* __restrict__ w2t, int* __restrict__ gcnt,
        int* __restrict__ cbase, float* __restrict__ dinv4,
        unsigned short* __restrict__ hbuf) {
    int bx = blockIdx.x;
    int t = threadIdx.x;
    if (bx < CAST_XBLK) {
        int i = bx * 256 + t;                // over N*D/4 float4 groups
        float4 v = ((const float4*)x)[i];
        ushort4 o;
        o.x = f2bf(v.x); o.y = f2bf(v.y); o.z = f2bf(v.z); o.w = f2bf(v.w);
        ((ushort4*)xb)[i] = o;
    } else if (bx < CAST_XBLK + CAST_WBLK) {
        int i = (bx - CAST_XBLK) * 256 + t;
        if (i < D_IN * H_DIM) {              // w1t[n][k] = W1[k][n]
            int k = i >> 8, n = i & 255;
            w1t[n * D_IN + k] = f2bf(W1[i]);
        } else {                             // w2t[n][k] = W2[k][n]
            int j = i - D_IN * H_DIM;
            int k = j >> 8, n = j & 255;
            w2t[n * H_DIM + k] = f2bf(W2[j]);
        }
    } else if (bx < PREP_CNT0) {
        // pad-row zeroing: dinv4 tail (pad weight), xb row N, hbuf row N
        dinv4[N4 + t] = 0.f;                                  // 256 floats
        if (t < 64)  ((unsigned int*)xb)[(size_t)N_NODES * 64 + t] = 0u;    // 128 bf16
        if (t < 128) ((unsigned int*)hbuf)[(size_t)N_NODES * 128 + t] = 0u; // 256 bf16
    } else {
        // ---- coarse histogram over 128 dst buckets (LDS atomics) ----
        __shared__ int cnt[NBKT];
        int bx2 = bx - PREP_CNT0;
        int s = bx2 / NCHK, c = bx2 - s * NCHK;
        if (t < NBKT) cnt[t] = 0;
        __syncthreads();
        const int* dstp = ei + (size_t)s * 2 * E_EDGES + E_EDGES;
        int base = c * CHK + t;
        #pragma unroll
        for (int k = 0; k < KPT; ++k) {
            int j = base + k * 256;
            if (j < E_EDGES) atomicAdd(&cnt[dstp[j] / BW_BKT], 1);
        }
        __syncthreads();
        if (t < NBKT) {
            int v = cnt[t];
            cbase[(size_t)bx2 * NBKT + t] = atomicAdd(&gcnt[s * NBKT + t], v);
        }
    }
}

// ---- tiny scan: bucket totals -> global bucket offsets ----
__global__ __launch_bounds__(512) void scan_gcnt_kernel(const int* __restrict__ gcnt,
        int* __restrict__ boffb) {
    __shared__ int sh[512];
    int t = threadIdx.x;
    int v = gcnt[t];                           // exactly NPB=512 entries
    sh[t] = v;
    __syncthreads();
    for (int off = 1; off < 512; off <<= 1) {
        int u = (t >= off) ? sh[t - off] : 0;
        __syncthreads();
        sh[t] += u;
        __syncthreads();
    }
    boffb[t] = sh[t] - v;                      // exclusive
}

// ---- pass 1b: partition edges into bucket-contiguous packed records ----
__global__ __launch_bounds__(256) void part_scatter_kernel(const int* __restrict__ ei,
        const int* __restrict__ boffb, const int* __restrict__ cbase,
        unsigned int* __restrict__ packed) {
    __shared__ int cnt[NBKT];
    __shared__ int sco[NBKT];
    __shared__ int lofs[NBKT + 1];
    __shared__ int cb2[NBKT];
    __shared__ unsigned int lbuf[CHK];         // 16 KB staging
    __shared__ unsigned char bbuf[CHK];        // 4 KB bucket ids (kills binary search)
    int bx = blockIdx.x;
    int s = bx / NCHK, c = bx - s * NCHK;
    int t = threadIdx.x;
    if (t < NBKT) cnt[t] = 0;
    __syncthreads();
    const int* srcp = ei + (size_t)s * 2 * E_EDGES;
    const int* dstp = srcp + E_EDGES;
    int base = c * CHK + t;
    unsigned int pv[KPT];
    int prb[KPT];                              // (bucket<<13) | rank  (rank < 4096)
    #pragma unroll
    for (int k = 0; k < KPT; ++k) {
        int j = base + k * 256;
        prb[k] = -1;
        if (j < E_EDGES) {
            int d = dstp[j];
            int b = d / BW_BKT;
            int dl = d - b * BW_BKT;           // < 782 -> 10 bits; src < 2^17
            pv[k] = (unsigned int)srcp[j] | ((unsigned int)dl << 17);
            int r = atomicAdd(&cnt[b], 1);     // LDS atomic
            prb[k] = (b << 13) | r;
        }
    }
    __syncthreads();
    if (t < NBKT) sco[t] = cnt[t];
    __syncthreads();
    for (int off = 1; off < NBKT; off <<= 1) { // exclusive scan over 128 counters
        int u = (t < NBKT && t >= off) ? sco[t - off] : 0;
        __syncthreads();
        if (t < NBKT) sco[t] += u;
        __syncthreads();
    }
    if (t < NBKT) {
        int ex = sco[t] - cnt[t];
        lofs[t] = ex;
        if (t == NBKT - 1) lofs[NBKT] = sco[t];
        cb2[t] = boffb[s * NBKT + t] + cbase[(size_t)bx * NBKT + t] - ex;
    }
    __syncthreads();
    #pragma unroll
    for (int k = 0; k < KPT; ++k) {
        if (prb[k] >= 0) {
            int b = prb[k] >> 13;
            int pos = lofs[b] + (prb[k] & 0x1FFF);
            lbuf[pos] = pv[k];
            bbuf[pos] = (unsigned char)b;
        }
    }
    __syncthreads();
    int tot = lofs[NBKT];
    for (int i = t; i < tot; i += 256) {       // consecutive i -> coalesced bucket runs
        packed[cb2[bbuf[i]] + i] = lbuf[i];
    }
}

// ---- pass 2: per-(snapshot,bucket) CSR build; padded rows (multiple of 8),
//      pad slots -> src N_NODES (zero row). rowinfo = (csr_start | pdeg<<24). ----
__global__ __launch_bounds__(1024) void bucket_csr_kernel(const unsigned int* __restrict__ packed,
        const int* __restrict__ gcnt, const int* __restrict__ boffb,
        unsigned int* __restrict__ rowinfo, float* __restrict__ dinv4,
        int* __restrict__ csrsrc4) {
    __shared__ int deg[BW_BKT];                // histogram, then cursor
    __shared__ int sc[1024];
    __shared__ unsigned int stg[CSR_CAP];      // 56 KB edge staging
    int bx = blockIdx.x;                       // s*NBKT + b
    int s = bx >> 7, b = bx & (NBKT - 1);
    int t = threadIdx.x;
    int ebase = boffb[bx];                     // packed (unpadded) region
    int pbase = ((ebase + 3) & ~3) + bx * PADCAP;  // csrsrc4 (padded, 16B-aligned rows)
    int ecnt = gcnt[bx];
    bool fits = (ecnt <= CSR_CAP);
    for (int i = t; i < BW_BKT; i += 1024) deg[i] = 0;
    __syncthreads();
    const unsigned int* pk = packed + ebase;
    if (fits) {
        for (int i = t; i < ecnt; i += 1024) {
            unsigned int p = pk[i];
            stg[i] = p;
            atomicAdd(&deg[p >> 17], 1);       // LDS atomic
        }
    } else {
        for (int i = t; i < ecnt; i += 1024) atomicAdd(&deg[pk[i] >> 17], 1);
    }
    __syncthreads();
    int d0 = (t < BW_BKT) ? deg[t] : 0;
    int pd = (d0 + 7) & ~7;                    // pad to multiple of 8
    sc[t] = pd;
    __syncthreads();
    for (int off = 1; off < 1024; off <<= 1) {
        int u = (t >= off) ? sc[t - off] : 0;
        __syncthreads();
        sc[t] += u;
        __syncthreads();
    }
    int pex = sc[t] - pd;                      // padded exclusive within bucket
    int g = b * BW_BKT + t;
    if (t < BW_BKT && g < N_NODES) {
        rowinfo[s * N_NODES + g] =
            (unsigned int)(pbase + pex) | ((unsigned int)pd << 24);
        dinv4[s * N_NODES + g] = rsqrtf((float)(d0 + 1));   // +1 self-loop
        for (int i = d0; i < pd; ++i) csrsrc4[pbase + pex + i] = N_NODES;  // pad slots
    }
    __syncthreads();
    if (t < BW_BKT) deg[t] = pex;              // becomes cursor (padded offsets)
    __syncthreads();
    if (fits) {
        for (int i = t; i < ecnt; i += 1024) {
            unsigned int p = stg[i];
            int r = atomicAdd(&deg[p >> 17], 1);   // LDS atomic, unique slot per dst
            csrsrc4[pbase + r] = (int)(p & 0x1FFFFu);
        }
    } else {
        for (int i = t; i < ecnt; i += 1024) {
            unsigned int p = pk[i];
            int r = atomicAdd(&deg[p >> 17], 1);
            csrsrc4[pbase + r] = (int)(p & 0x1FFFFu);
        }
    }
}

// ---- one 8-edge batch for the feature aggregation (2 bf16/lane rows) ----
__device__ __forceinline__ void xbatch8(const int* __restrict__ csrsrc4, int e,
        const unsigned int* __restrict__ tp, const float* __restrict__ dv,
        float di, int lane, float& ax, float& ay) {
    int4 q0 = *(const int4*)(csrsrc4 + e);
    int4 q1 = *(const int4*)(csrsrc4 + e + 4);
    float w0 = dv[q0.x] * di, w1 = dv[q0.y] * di, w2 = dv[q0.z] * di, w3 = dv[q0.w] * di;
    float w4 = dv[q1.x] * di, w5 = dv[q1.y] * di, w6 = dv[q1.z] * di, w7 = dv[q1.w] * di;
    unsigned int u0 = tp[(size_t)q0.x * 64 + lane];
    unsigned int u1 = tp[(size_t)q0.y * 64 + lane];
    unsigned int u2 = tp[(size_t)q0.z * 64 + lane];
    unsigned int u3 = tp[(size_t)q0.w * 64 + lane];
    unsigned int u4 = tp[(size_t)q1.x * 64 + lane];
    unsigned int u5 = tp[(size_t)q1.y * 64 + lane];
    unsigned int u6 = tp[(size_t)q1.z * 64 + lane];
    unsigned int u7 = tp[(size_t)q1.w * 64 + lane];
    ax = fmaf(bf2f((unsigned short)(u0 & 0xffffu)), w0, ax);
    ay = fmaf(bf2f((unsigned short)(u0 >> 16)),     w0, ay);
    ax = fmaf(bf2f((unsigned short)(u1 & 0xffffu)), w1, ax);
    ay = fmaf(bf2f((unsigned short)(u1 >> 16)),     w1, ay);
    ax = fmaf(bf2f((unsigned short)(u2 & 0xffffu)), w2, ax);
    ay = fmaf(bf2f((unsigned short)(u2 >> 16)),     w2, ay);
    ax = fmaf(bf2f((unsigned short)(u3 & 0xffffu)), w3, ax);
    ay = fmaf(bf2f((unsigned short)(u3 >> 16)),     w3, ay);
    ax = fmaf(bf2f((unsigned short)(u4 & 0xffffu)), w4, ax);
    ay = fmaf(bf2f((unsigned short)(u4 >> 16)),     w4, ay);
    ax = fmaf(bf2f((unsigned short)(u5 & 0xffffu)), w5, ax);
    ay = fmaf(bf2f((unsigned short)(u5 >> 16)),     w5, ay);
    ax = fmaf(bf2f((unsigned short)(u6 & 0xffffu)), w6, ax);
    ay = fmaf(bf2f((unsigned short)(u6 >> 16)),     w6, ay);
    ax = fmaf(bf2f((unsigned short)(u7 & 0xffffu)), w7, ax);
    ay = fmaf(bf2f((unsigned short)(u7 >> 16)),     w7, ay);
}

// ------- SpMM layer 0, SNAPSHOT-FUSED: grid = fuseN x 12500 blocks, interleaved.
//         Body identical to the verified dual-chain kernel. -------
__global__ __launch_bounds__(256) void spmm_x_kernel(const unsigned short* __restrict__ xb,
        const float* __restrict__ dinv4, const unsigned int* __restrict__ rowinfo,
        const int* __restrict__ csrsrc4, unsigned short* __restrict__ agg0,
        int sbase, int fuseN) {
    int bx = blockIdx.x;
    int sl = bx % fuseN;                       // interleave snapshots across XCDs
    int rblk = bx / fuseN;
    int soff = (sbase + sl) * N_NODES;
    int wid = threadIdx.x >> 6;
    int lane = threadIdx.x & 63;
    int rA = (rblk << 3) + (wid << 1);         // 8 rows/block, 2 per wave
    int rB = rA + 1;
    const unsigned int* tp = (const unsigned int*)xb;   // 1 uint = 2 bf16; row = 64 uints
    const float* dv = dinv4 + soff;
    unsigned int riA = rowinfo[soff + rA];
    unsigned int riB = rowinfo[soff + rB];
    int eA = (int)(riA & 0xFFFFFFu), e1A = eA + (int)(riA >> 24);
    int eB = (int)(riB & 0xFFFFFFu), e1B = eB + (int)(riB >> 24);
    float diA = dv[rA], diB = dv[rB];
    float axA = 0.f, ayA = 0.f, axB = 0.f, ayB = 0.f;
    while (eA < e1A && eB < e1B) {             // dual-chain: loads overlap across A/B
        xbatch8(csrsrc4, eA, tp, dv, diA, lane, axA, ayA);
        xbatch8(csrsrc4, eB, tp, dv, diB, lane, axB, ayB);
        eA += 8; eB += 8;
    }
    while (eA < e1A) { xbatch8(csrsrc4, eA, tp, dv, diA, lane, axA, ayA); eA += 8; }
    while (eB < e1B) { xbatch8(csrsrc4, eB, tp, dv, diB, lane, axB, ayB); eB += 8; }
    unsigned int usA = tp[(size_t)rA * 64 + lane];      // self rows
    unsigned int usB = tp[(size_t)rB * 64 + lane];
    float wdA = diA * diA, wdB = diB * diB;
    axA = fmaf(bf2f((unsigned short)(usA & 0xffffu)), wdA, axA);
    ayA = fmaf(bf2f((unsigned short)(usA >> 16)),     wdA, ayA);
    axB = fmaf(bf2f((unsigned short)(usB & 0xffffu)), wdB, axB);
    ayB = fmaf(bf2f((unsigned short)(usB >> 16)),     wdB, ayB);
    unsigned int* outp = (unsigned int*)agg0 + (size_t)sl * N_NODES * 64;
    outp[(size_t)rA * 64 + lane] =
        (unsigned int)f2bf(axA) | ((unsigned int)f2bf(ayA) << 16);
    outp[(size_t)rB * 64 + lane] =
        (unsigned int)f2bf(axB) | ((unsigned int)f2bf(ayB) << 16);
}

// ------- MFMA GEMM per snapshot: h = relu(agg0 @ W1 + b1)   [N,256] bf16.
//         FULL-ROW blocks (1563): A-tile staged once, A-frags hoisted to regs,
//         B read straight from L2-hot w1t (r6-precedented), output restaged into
//         the same LDS tile via the r10 wave-private-rows idiom, then full
//         512B-row coalesced stores. A traffic 4x -> 1x vs quadrant version. -------
__global__ __launch_bounds__(256) void gemm_h_mfma(const unsigned short* __restrict__ A,
        const unsigned short* __restrict__ w1t, const float* __restrict__ b1,
        unsigned short* __restrict__ h, int M) {
    __shared__ unsigned short S[64][264];    // A cols 0..127 first, then full output stage
    int tid = threadIdx.x;
    int m0 = blockIdx.x * 64;
    {
        int row = tid >> 2, c0 = (tid & 3) * 32;
        int gm = m0 + row;
        #pragma unroll
        for (int ii = 0; ii < 4; ++ii) {
            uint4 v = make_uint4(0u, 0u, 0u, 0u);
            if (gm < M) v = *(const uint4*)(A + (size_t)gm * D_IN + c0 + ii * 8);
            *(uint4*)&S[row][c0 + ii * 8] = v;
        }
    }
    __syncthreads();
    int w = tid >> 6, l = tid & 63;
    int q = l >> 4, mrow = l & 15;
    int arow = 16 * w + mrow;                // wave-private row set [16w,16w+16)
    bf16x8 af0 = *(const bf16x8*)&S[arow][0  + q * 8];
    bf16x8 af1 = *(const bf16x8*)&S[arow][32 + q * 8];
    bf16x8 af2 = *(const bf16x8*)&S[arow][64 + q * 8];
    bf16x8 af3 = *(const bf16x8*)&S[arow][96 + q * 8];
    #pragma unroll
    for (int ct = 0; ct < 16; ++ct) {
        int n = ct * 16 + mrow;
        const unsigned short* wp = w1t + (size_t)n * D_IN + q * 8;
        f32x4 acc = {0.f, 0.f, 0.f, 0.f};
        acc = __builtin_amdgcn_mfma_f32_16x16x32_bf16(af0, *(const bf16x8*)(wp + 0),  acc, 0, 0, 0);
        acc = __builtin_amdgcn_mfma_f32_16x16x32_bf16(af1, *(const bf16x8*)(wp + 32), acc, 0, 0, 0);
        acc = __builtin_amdgcn_mfma_f32_16x16x32_bf16(af2, *(const bf16x8*)(wp + 64), acc, 0, 0, 0);
        acc = __builtin_amdgcn_mfma_f32_16x16x32_bf16(af3, *(const bf16x8*)(wp + 96), acc, 0, 0, 0);
        float bias = b1[n];
        // restage: wave w writes ONLY its own rows (acc dep orders after frag reads)
        #pragma unroll
        for (int ii = 0; ii < 4; ++ii)
            S[16 * w + q * 4 + ii][n] = f2bf(fmaxf(acc[ii] + bias, 0.f));
    }
    __syncthreads();
    // coalesced store: 64 rows x 512 B full rows; 8 passes of 8 rows
    #pragma unroll
    for (int it = 0; it < 8; ++it) {
        int row = (tid >> 5) + it * 8;
        int c = (tid & 31) * 8;              // shorts; 16 B per thread
        int m = m0 + row;
        if (m < M)
            *(uint4*)&h[(size_t)m * H_DIM + c] = *(const uint4*)&S[row][c];
    }
}

// --- SpMM layer 1 (post rows), accumulating across snapshots; padded batches ---
__global__ __launch_bounds__(256) void spmm_h_post_kernel(const unsigned short* __restrict__ h,
        const float* __restrict__ dinv4, const unsigned int* __restrict__ rowinfo,
        const int* __restrict__ csrsrc4, const int* __restrict__ post,
        float* __restrict__ t1acc, float* __restrict__ hacc, int soff, int first) {
    int p = (blockIdx.x << 2) + (threadIdx.x >> 6);
    int lane = threadIdx.x & 63;
    int r = post[p];
    int rg = soff + r;
    unsigned int ri = rowinfo[rg];
    int e0 = (int)(ri & 0xFFFFFFu);
    int e1 = e0 + (int)(ri >> 24);
    float di = dinv4[rg];
    float4 acc = make_float4(0.f, 0.f, 0.f, 0.f);
    const ushort4* hp = (const ushort4*)h;
    const float* dv = dinv4 + soff;
    for (int e = e0; e + 8 <= e1; e += 8) {    // pdeg multiple of 8: exact coverage
        int4 q0 = *(const int4*)(csrsrc4 + e);
        int4 q1 = *(const int4*)(csrsrc4 + e + 4);
        int ss[8] = {q0.x, q0.y, q0.z, q0.w, q1.x, q1.y, q1.z, q1.w};
        float ww[8]; ushort4 uu[8];
        #pragma unroll
        for (int k = 0; k < 8; ++k) ww[k] = dv[ss[k]] * di;
        #pragma unroll
        for (int k = 0; k < 8; ++k) uu[k] = hp[(size_t)ss[k] * 64 + lane];
        #pragma unroll
        for (int k = 0; k < 8; ++k) {
            acc.x = fmaf(bf2f(uu[k].x), ww[k], acc.x);
            acc.y = fmaf(bf2f(uu[k].y), ww[k], acc.y);
            acc.z = fmaf(bf2f(uu[k].z), ww[k], acc.z);
            acc.w = fmaf(bf2f(uu[k].w), ww[k], acc.w);
        }
    }
    ushort4 u = hp[(size_t)r * 64 + lane];        // self row = h_s[post[p]]
    float hx = bf2f(u.x), hy = bf2f(u.y), hz = bf2f(u.z), hw = bf2f(u.w);
    float wd = di * di;
    acc.x = fmaf(hx, wd, acc.x);
    acc.y = fmaf(hy, wd, acc.y);
    acc.z = fmaf(hz, wd, acc.z);
    acc.w = fmaf(hw, wd, acc.w);
    size_t idx = (size_t)p * 64 + lane;
    float4 hv = make_float4(hx, hy, hz, hw);
    if (first) {
        ((float4*)t1acc)[idx] = acc;
        ((float4*)hacc)[idx] = hv;
    } else {
        float4 a = ((float4*)t1acc)[idx];
        a.x += acc.x; a.y += acc.y; a.z += acc.z; a.w += acc.w;
        ((float4*)t1acc)[idx] = a;
        float4 b = ((float4*)hacc)[idx];
        b.x += hv.x; b.y += hv.y; b.z += hv.z; b.w += hv.w;
        ((float4*)hacc)[idx] = b;
    }
}

// ------- MFMA GEMM layer 1 (ONCE): accP = t1acc @ W2 + 4*b2 + hacc -------
__global__ __launch_bounds__(256) void gemm_l1_mfma(const float* __restrict__ A,
        const unsigned short* __restrict__ w2t, const float* __restrict__ b2,
        const float* __restrict__ hacc, float* __restrict__ accP, int M) {
    __shared__ unsigned short As[64][136];
    __shared__ unsigned short Bs[64][136];
    int tid = threadIdx.x;
    int n0 = blockIdx.x * 64, m0 = blockIdx.y * 64;
    int w = tid >> 6, l = tid & 63;
    int q = l >> 4, mrow = l & 15;
    f32x4 acc[4] = {{0.f,0.f,0.f,0.f},{0.f,0.f,0.f,0.f},{0.f,0.f,0.f,0.f},{0.f,0.f,0.f,0.f}};
    for (int kk = 0; kk < 256; kk += 128) {
        __syncthreads();
        {
            int row = tid >> 2, c0 = (tid & 3) * 32;
            int gm = m0 + row;
            #pragma unroll
            for (int i = 0; i < 8; ++i) {
                float4 v = make_float4(0.f, 0.f, 0.f, 0.f);
                if (gm < M) v = *(const float4*)(A + (size_t)gm * 256 + kk + c0 + i * 4);
                As[row][c0 + i * 4 + 0] = f2bf(v.x);
                As[row][c0 + i * 4 + 1] = f2bf(v.y);
                As[row][c0 + i * 4 + 2] = f2bf(v.z);
                As[row][c0 + i * 4 + 3] = f2bf(v.w);
            }
        }
        {
            int n = tid >> 2, k0 = (tid & 3) * 32;
            #pragma unroll
            for (int i = 0; i < 4; ++i) {
                *(uint4*)&Bs[n][k0 + i * 8] =
                    *(const uint4*)(w2t + (size_t)(n0 + n) * H_DIM + kk + k0 + i * 8);
            }
        }
        __syncthreads();
        #pragma unroll
        for (int ks = 0; ks < 4; ++ks) {
            bf16x8 a = *(const bf16x8*)&As[16 * w + mrow][ks * 32 + q * 8];
            #pragma unroll
            for (int ct = 0; ct < 4; ++ct) {
                bf16x8 b = *(const bf16x8*)&Bs[ct * 16 + mrow][ks * 32 + q * 8];
                acc[ct] = __builtin_amdgcn_mfma_f32_16x16x32_bf16(a, b, acc[ct], 0, 0, 0);
            }
        }
    }
    #pragma unroll
    for (int ct = 0; ct < 4; ++ct) {
        int col = n0 + ct * 16 + mrow;
        float bias = 4.0f * b2[col];
        #pragma unroll
        for (int i = 0; i < 4; ++i) {
            int m = m0 + 16 * w + q * 4 + i;
            if (m < M) {
                accP[(size_t)m * 256 + col] =
                    acc[ct][i] + bias + hacc[(size_t)m * 256 + col];
            }
        }
    }
}

// ---------------- classifier ----------------
__global__ __launch_bounds__(128) void classifier_kernel(const float* __restrict__ accP,
        const float* __restrict__ Wc1, const float* __restrict__ bc1,
        const float* __restrict__ Wc2, const float* __restrict__ bc2,
        float* __restrict__ out) {
    __shared__ float arow[8][256];
    __shared__ float red[2][8];
    int p0 = blockIdx.x << 3;
    int tid = threadIdx.x;
    for (int idx = tid; idx < 8 * 256; idx += 128) {
        int pl = idx >> 8, k = idx & 255;
        arow[pl][k] = 0.25f * accP[(size_t)(p0 + pl) * 256 + k];
    }
    __syncthreads();
    float s[8];
    float b = bc1[tid];
    #pragma unroll
    for (int pl = 0; pl < 8; ++pl) s[pl] = b;
    for (int k = 0; k < 256; ++k) {
        float wv = Wc1[k * 128 + tid];
        #pragma unroll
        for (int pl = 0; pl < 8; ++pl) s[pl] = fmaf(arow[pl][k], wv, s[pl]);
    }
    float wc2 = Wc2[tid];
    float part[8];
    #pragma unroll
    for (int pl = 0; pl < 8; ++pl) part[pl] = fmaxf(s[pl], 0.f) * wc2;
    #pragma unroll
    for (int off = 32; off > 0; off >>= 1)
        #pragma unroll
        for (int pl = 0; pl < 8; ++pl) part[pl] += __shfl_down(part[pl], off, 64);
    int wave = tid >> 6, lane = tid & 63;
    if (lane == 0) {
        #pragma unroll
        for (int pl = 0; pl < 8; ++pl) red[wave][pl] = part[pl];
    }
    __syncthreads();
    if (tid < 8) {
        float logit = red[0][tid] + red[1][tid] + bc2[0];
        out[p0 + tid] = 1.f / (1.f + expf(-logit));
    }
}

extern "C" void kernel_launch(void* const* d_in, const int* in_sizes, int n_in,
                              void* d_out, int out_size, void* d_ws, size_t ws_size,
                              hipStream_t stream) {
    const float* x   = (const float*)d_in[0];
    const int*   ei  = (const int*)d_in[1];
    const int*   post= (const int*)d_in[2];
    const float* W1  = (const float*)d_in[3];
    const float* b1  = (const float*)d_in[4];
    const float* W2  = (const float*)d_in[5];
    const float* b2  = (const float*)d_in[6];
    const float* Wc1 = (const float*)d_in[7];
    const float* bc1 = (const float*)d_in[8];
    const float* Wc2 = (const float*)d_in[9];
    const float* bc2 = (const float*)d_in[10];
    float* out = (float*)d_out;

    // snapshot-fusion factor, chosen by available workspace (graceful fallback)
    const size_t NEED4 = 242000000ull;       // ~240.8 MB actual
    const size_t NEED2 = 191000000ull;       // ~189.6 MB actual
    int fuseN = (ws_size >= NEED4) ? 4 : ((ws_size >= NEED2) ? 2 : 1);

    char* w = (char*)d_ws;
    size_t off = 0;
#define WS_ALLOC(type, name, count) \
    type* name = (type*)(w + off); \
    off += (((size_t)(count) * sizeof(type)) + 255) & ~(size_t)255;
    WS_ALLOC(unsigned short, xb,      (size_t)(N_NODES + 1) * D_IN)  // 25.6 MB (+zero row)
    WS_ALLOC(unsigned short, agg0,    (size_t)fuseN * N_NODES * D_IN) // 25.6*fuseN MB (accP aliases)
    WS_ALLOC(unsigned short, hbuf,    (size_t)(N_NODES + 1) * H_DIM) // 51.2 MB (+zero row; packed aliases)
    WS_ALLOC(float,          t1acc,   (size_t)P_POST * H_DIM)        // 10.24 MB
    WS_ALLOC(float,          hacc,    (size_t)P_POST * H_DIM)        // 10.24 MB
    WS_ALLOC(float,          dinv4,   N4 + 256)                      // 1.6 MB (+zero pad tail)
    WS_ALLOC(unsigned int,   rowinfo, N4)                            // 1.6 MB (ptr|pdeg<<24)
    WS_ALLOC(int,            csrsrc4, CSRSZ)                         // 36.8 MB (padded CSR)
    WS_ALLOC(int,            cbase,   (size_t)S_SNAP * NCHK * NBKT)  // 0.8 MB
    WS_ALLOC(int,            gcnt,    NPB)
    WS_ALLOC(int,            boffb,   NPB)
    WS_ALLOC(unsigned short, w1t,     (size_t)H_DIM * D_IN)          // 64 KB  W1^T bf16
    WS_ALLOC(unsigned short, w2t,     (size_t)H_DIM * H_DIM)         // 128 KB W2^T bf16
#undef WS_ALLOC
    // packed[E4] u32 (25.6 MB) aliases hbuf rows 0..50K: consumed by bucket_csr before
    //   any gemm_h writes h; hbuf zero-row (offset 51.2 MB) is beyond packed.
    // accP [P,256] fp32 (10.24 MB) aliases agg0: agg0 dead after last gemm_h.
    unsigned int* packed = (unsigned int*)hbuf;
    float* accP = (float*)agg0;
    (void)in_sizes; (void)n_in; (void)out_size;

    // gcnt zero via async memset (graph-capture-safe), then fused prep:
    // X cast + W transpose-cast + pad-row zero + coarse histogram in ONE dispatch.
    hipMemsetAsync(gcnt, 0, NPB * sizeof(int), stream);
    prep_kernel<<<PREP_GRID, 256, 0, stream>>>(x, W1, W2, ei, xb, w1t, w2t,
                                               gcnt, cbase, dinv4, hbuf);
    scan_gcnt_kernel<<<1, 512, 0, stream>>>(gcnt, boffb);
    part_scatter_kernel<<<S_SNAP * NCHK, 256, 0, stream>>>(ei, boffb, cbase, packed);
    bucket_csr_kernel<<<NPB, 1024, 0, stream>>>(packed, gcnt, boffb, rowinfo, dinv4, csrsrc4);

    for (int g = 0; g < S_SNAP; g += fuseN) {
        // agg0[sl] = Ahat_{g+sl} @ Xbf16  — fuseN snapshots in ONE dispatch
        spmm_x_kernel<<<fuseN * (N_NODES / 8), 256, 0, stream>>>(
            xb, dinv4, rowinfo, csrsrc4, agg0, g, fuseN);
        for (int sl = 0; sl < fuseN; ++sl) {
            int s = g + sl;
            // h = relu(agg0[sl] @ W1 + b1)   [N,256] bf16  (full-row blocks)
            gemm_h_mfma<<<GH_MTILES, 256, 0, stream>>>(
                agg0 + (size_t)sl * N_NODES * D_IN, w1t, b1, hbuf, N_NODES);
            // t1acc (+)= (Ahat @ h)[post];  hacc (+)= h[post]
            spmm_h_post_kernel<<<P_POST / 4, 256, 0, stream>>>(
                hbuf, dinv4, rowinfo, csrsrc4, post, t1acc, hacc, s * N_NODES, s == 0);
        }
    }
    // accP = t1acc @ W2 + 4*b2 + hacc   — single bf16 MFMA GEMM (W2 snapshot-invariant)
    dim3 g1(H_DIM / 64, (P_POST + 63) / 64);
    gemm_l1_mfma<<<g1, 256, 0, stream>>>(t1acc, w2t, b2, hacc, accP, P_POST);

    classifier_kernel<<<P_POST / 8, 128, 0, stream>>>(accP, Wc1, bc1, Wc2, bc2, out);
}

// Round 13
// 667.406 us; speedup vs baseline: 1.2030x; 1.2030x over previous
//
#include <hip/hip_runtime.h>
#include <math.h>

#define N_NODES 100000
#define E_EDGES 1600000
#define S_SNAP  4
#define D_IN    128
#define H_DIM   256
#define P_POST  10000
#define N4 (S_SNAP * N_NODES)               // 400000
#define E4 (S_SNAP * E_EDGES)               // 6400000

// ---- counting-sort graph prep (single-pass partition) ----
#define NBKT 128                             // coarse dst buckets per snapshot
#define BW_BKT 782                           // 128*782 = 100096 >= N_NODES
#define CHK 4096                             // edges per partition block
#define KPT (CHK / 256)                      // 16 edges per thread
#define NCHK ((E_EDGES + CHK - 1) / CHK)     // 391 chunks per snapshot
#define NPB (S_SNAP * NBKT)                  // 512 (snapshot,bucket) units
#define CAPB 14336                           // fixed packed capacity/bucket (16sigma slack)
#define CSR_CAP 14336                        // LDS staging cap in bucket_csr
#define PADCAP 5480                          // per-bucket pad slack: 7*782=5474 worst +align
#define CSRSZ (E4 + NPB * PADCAP + 8)        // 9,205,768 < 2^24 (dense padded CSR)

// ---- prep kernel block ranges: xb cast | w cast | pad-zero (count pass DELETED) ----
#define CAST_XBLK (N_NODES * D_IN / 4 / 256)                  // 12500
#define CAST_WBLK ((D_IN * H_DIM + H_DIM * H_DIM) / 256)      // 384
#define PREP_GRID (CAST_XBLK + CAST_WBLK + 1)                 // 12885

// ---- gemm_h XCD swizzle (r11-verified quadrant version) ----
#define GH_MTILES ((N_NODES + 63) / 64)      // 1563
#define GH_GRID   6272                       // 8 XCD * 784; maps mg<=1567, 20 blocks idle

typedef __attribute__((ext_vector_type(8))) short bf16x8;   // MFMA A/B frag (4 VGPRs)
typedef __attribute__((ext_vector_type(4))) float f32x4;    // MFMA C/D frag

// ---------- bf16 helpers ----------
__device__ __forceinline__ float bf2f(unsigned short u) {
    union { unsigned int i; float f; } v; v.i = ((unsigned int)u) << 16; return v.f;
}
__device__ __forceinline__ unsigned short f2bf(float f) {
    union { float f; unsigned int i; } v; v.f = f;
    unsigned int lsb = (v.i >> 16) & 1u;
    v.i += 0x7fffu + lsb;                 // round-nearest-even
    return (unsigned short)(v.i >> 16);
}

// ---- prep: X cast + W transpose-cast + pad-row zero (no more histogram pass) ----
__global__ __launch_bounds__(256) void prep_kernel(const float* __restrict__ x,
        const float* __restrict__ W1, const float* __restrict__ W2,
        unsigned short* __restrict__ xb, unsigned short* __restrict__ w1t,
        unsigned short* __restrict__ w2t, float* __restrict__ dinv4,
        unsigned short* __restrict__ hbuf) {
    int bx = blockIdx.x;
    int t = threadIdx.x;
    if (bx < CAST_XBLK) {
        int i = bx * 256 + t;                // over N*D/4 float4 groups
        float4 v = ((const float4*)x)[i];
        ushort4 o;
        o.x = f2bf(v.x); o.y = f2bf(v.y); o.z = f2bf(v.z); o.w = f2bf(v.w);
        ((ushort4*)xb)[i] = o;
    } else if (bx < CAST_XBLK + CAST_WBLK) {
        int i = (bx - CAST_XBLK) * 256 + t;
        if (i < D_IN * H_DIM) {              // w1t[n][k] = W1[k][n]
            int k = i >> 8, n = i & 255;
            w1t[n * D_IN + k] = f2bf(W1[i]);
        } else {                             // w2t[n][k] = W2[k][n]
            int j = i - D_IN * H_DIM;
            int k = j >> 8, n = j & 255;
            w2t[n * H_DIM + k] = f2bf(W2[j]);
        }
    } else {
        // pad-row zeroing: dinv4 tail (pad weight), xb row N, hbuf row N
        dinv4[N4 + t] = 0.f;                                  // 256 floats
        if (t < 64)  ((unsigned int*)xb)[(size_t)N_NODES * 64 + t] = 0u;    // 128 bf16
        if (t < 128) ((unsigned int*)hbuf)[(size_t)N_NODES * 128 + t] = 0u; // 256 bf16
    }
}

// ---- SINGLE-PASS partition: LDS-count + direct atomic reservation into
//      fixed-capacity bucket regions of `packed` (kills the part_count pass). ----
__global__ __launch_bounds__(256) void part_scatter_kernel(const int* __restrict__ ei,
        int* __restrict__ gcnt, unsigned int* __restrict__ packed) {
    __shared__ int cnt[NBKT];
    __shared__ int sco[NBKT];
    __shared__ int lofs[NBKT + 1];
    __shared__ int cb2[NBKT];
    __shared__ unsigned int lbuf[CHK];         // 16 KB staging
    __shared__ unsigned char bbuf[CHK];        // 4 KB bucket ids
    int bx = blockIdx.x;
    int s = bx / NCHK, c = bx - s * NCHK;
    int t = threadIdx.x;
    if (t < NBKT) cnt[t] = 0;
    __syncthreads();
    const int* srcp = ei + (size_t)s * 2 * E_EDGES;
    const int* dstp = srcp + E_EDGES;
    int base = c * CHK + t;
    unsigned int pv[KPT];
    int prb[KPT];                              // (bucket<<13) | rank  (rank < 4096)
    #pragma unroll
    for (int k = 0; k < KPT; ++k) {
        int j = base + k * 256;
        prb[k] = -1;
        if (j < E_EDGES) {
            int d = dstp[j];
            int b = d / BW_BKT;
            int dl = d - b * BW_BKT;           // < 782 -> 10 bits; src < 2^17
            pv[k] = (unsigned int)srcp[j] | ((unsigned int)dl << 17);
            int r = atomicAdd(&cnt[b], 1);     // LDS atomic
            prb[k] = (b << 13) | r;
        }
    }
    __syncthreads();
    if (t < NBKT) sco[t] = cnt[t];
    __syncthreads();
    for (int off = 1; off < NBKT; off <<= 1) { // exclusive scan over 128 counters
        int u = (t < NBKT && t >= off) ? sco[t - off] : 0;
        __syncthreads();
        if (t < NBKT) sco[t] += u;
        __syncthreads();
    }
    if (t < NBKT) {
        int ex = sco[t] - cnt[t];
        lofs[t] = ex;
        if (t == NBKT - 1) lofs[NBKT] = sco[t];
        // direct reservation: base within this bucket's fixed region
        int rbase = atomicAdd(&gcnt[s * NBKT + t], cnt[t]);
        cb2[t] = (s * NBKT + t) * CAPB + rbase - ex;
    }
    __syncthreads();
    #pragma unroll
    for (int k = 0; k < KPT; ++k) {
        if (prb[k] >= 0) {
            int b = prb[k] >> 13;
            int pos = lofs[b] + (prb[k] & 0x1FFF);
            lbuf[pos] = pv[k];
            bbuf[pos] = (unsigned char)b;
        }
    }
    __syncthreads();
    int tot = lofs[NBKT];
    for (int i = t; i < tot; i += 256) {       // consecutive i -> coalesced bucket runs
        packed[cb2[bbuf[i]] + i] = lbuf[i];
    }
}

// ---- tiny scan (AFTER scatter): bucket totals -> dense csrsrc offsets ----
__global__ __launch_bounds__(512) void scan_gcnt_kernel(const int* __restrict__ gcnt,
        int* __restrict__ boffb) {
    __shared__ int sh[512];
    int t = threadIdx.x;
    int v = gcnt[t];                           // exactly NPB=512 entries
    sh[t] = v;
    __syncthreads();
    for (int off = 1; off < 512; off <<= 1) {
        int u = (t >= off) ? sh[t - off] : 0;
        __syncthreads();
        sh[t] += u;
        __syncthreads();
    }
    boffb[t] = sh[t] - v;                      // exclusive
}

// ---- pass 2: per-(snapshot,bucket) CSR build; packed read from FIXED region,
//      csrsrc written densely (padded rows, multiple of 8; pads -> zero row). ----
__global__ __launch_bounds__(1024) void bucket_csr_kernel(const unsigned int* __restrict__ packed,
        const int* __restrict__ gcnt, const int* __restrict__ boffb,
        unsigned int* __restrict__ rowinfo, float* __restrict__ dinv4,
        int* __restrict__ csrsrc4) {
    __shared__ int deg[BW_BKT];                // histogram, then cursor
    __shared__ int sc[1024];
    __shared__ unsigned int stg[CSR_CAP];      // 56 KB edge staging
    int bx = blockIdx.x;                       // s*NBKT + b
    int s = bx >> 7, b = bx & (NBKT - 1);
    int t = threadIdx.x;
    int ebase = boffb[bx];                     // dense (unpadded) running offset
    int pbase = ((ebase + 3) & ~3) + bx * PADCAP;  // csrsrc4 (padded, 16B-aligned rows)
    int ecnt = gcnt[bx];
    bool fits = (ecnt <= CSR_CAP);
    for (int i = t; i < BW_BKT; i += 1024) deg[i] = 0;
    __syncthreads();
    const unsigned int* pk = packed + (size_t)bx * CAPB;   // fixed-capacity region
    if (fits) {
        for (int i = t; i < ecnt; i += 1024) {
            unsigned int p = pk[i];
            stg[i] = p;
            atomicAdd(&deg[p >> 17], 1);       // LDS atomic
        }
    } else {
        for (int i = t; i < ecnt; i += 1024) atomicAdd(&deg[pk[i] >> 17], 1);
    }
    __syncthreads();
    int d0 = (t < BW_BKT) ? deg[t] : 0;
    int pd = (d0 + 7) & ~7;                    // pad to multiple of 8
    sc[t] = pd;
    __syncthreads();
    for (int off = 1; off < 1024; off <<= 1) {
        int u = (t >= off) ? sc[t - off] : 0;
        __syncthreads();
        sc[t] += u;
        __syncthreads();
    }
    int pex = sc[t] - pd;                      // padded exclusive within bucket
    int g = b * BW_BKT + t;
    if (t < BW_BKT && g < N_NODES) {
        rowinfo[s * N_NODES + g] =
            (unsigned int)(pbase + pex) | ((unsigned int)pd << 24);
        dinv4[s * N_NODES + g] = rsqrtf((float)(d0 + 1));   // +1 self-loop
        for (int i = d0; i < pd; ++i) csrsrc4[pbase + pex + i] = N_NODES;  // pad slots
    }
    __syncthreads();
    if (t < BW_BKT) deg[t] = pex;              // becomes cursor (padded offsets)
    __syncthreads();
    if (fits) {
        for (int i = t; i < ecnt; i += 1024) {
            unsigned int p = stg[i];
            int r = atomicAdd(&deg[p >> 17], 1);   // LDS atomic, unique slot per dst
            csrsrc4[pbase + r] = (int)(p & 0x1FFFFu);
        }
    } else {
        for (int i = t; i < ecnt; i += 1024) {
            unsigned int p = pk[i];
            int r = atomicAdd(&deg[p >> 17], 1);
            csrsrc4[pbase + r] = (int)(p & 0x1FFFFu);
        }
    }
}

// ---- one 8-edge batch for the feature aggregation (2 bf16/lane rows) ----
__device__ __forceinline__ void xbatch8(const int* __restrict__ csrsrc4, int e,
        const unsigned int* __restrict__ tp, const float* __restrict__ dv,
        float di, int lane, float& ax, float& ay) {
    int4 q0 = *(const int4*)(csrsrc4 + e);
    int4 q1 = *(const int4*)(csrsrc4 + e + 4);
    float w0 = dv[q0.x] * di, w1 = dv[q0.y] * di, w2 = dv[q0.z] * di, w3 = dv[q0.w] * di;
    float w4 = dv[q1.x] * di, w5 = dv[q1.y] * di, w6 = dv[q1.z] * di, w7 = dv[q1.w] * di;
    unsigned int u0 = tp[(size_t)q0.x * 64 + lane];
    unsigned int u1 = tp[(size_t)q0.y * 64 + lane];
    unsigned int u2 = tp[(size_t)q0.z * 64 + lane];
    unsigned int u3 = tp[(size_t)q0.w * 64 + lane];
    unsigned int u4 = tp[(size_t)q1.x * 64 + lane];
    unsigned int u5 = tp[(size_t)q1.y * 64 + lane];
    unsigned int u6 = tp[(size_t)q1.z * 64 + lane];
    unsigned int u7 = tp[(size_t)q1.w * 64 + lane];
    ax = fmaf(bf2f((unsigned short)(u0 & 0xffffu)), w0, ax);
    ay = fmaf(bf2f((unsigned short)(u0 >> 16)),     w0, ay);
    ax = fmaf(bf2f((unsigned short)(u1 & 0xffffu)), w1, ax);
    ay = fmaf(bf2f((unsigned short)(u1 >> 16)),     w1, ay);
    ax = fmaf(bf2f((unsigned short)(u2 & 0xffffu)), w2, ax);
    ay = fmaf(bf2f((unsigned short)(u2 >> 16)),     w2, ay);
    ax = fmaf(bf2f((unsigned short)(u3 & 0xffffu)), w3, ax);
    ay = fmaf(bf2f((unsigned short)(u3 >> 16)),     w3, ay);
    ax = fmaf(bf2f((unsigned short)(u4 & 0xffffu)), w4, ax);
    ay = fmaf(bf2f((unsigned short)(u4 >> 16)),     w4, ay);
    ax = fmaf(bf2f((unsigned short)(u5 & 0xffffu)), w5, ax);
    ay = fmaf(bf2f((unsigned short)(u5 >> 16)),     w5, ay);
    ax = fmaf(bf2f((unsigned short)(u6 & 0xffffu)), w6, ax);
    ay = fmaf(bf2f((unsigned short)(u6 >> 16)),     w6, ay);
    ax = fmaf(bf2f((unsigned short)(u7 & 0xffffu)), w7, ax);
    ay = fmaf(bf2f((unsigned short)(u7 >> 16)),     w7, ay);
}

// ------- SpMM layer 0, SNAPSHOT-FUSED (r11-verified) -------
__global__ __launch_bounds__(256) void spmm_x_kernel(const unsigned short* __restrict__ xb,
        const float* __restrict__ dinv4, const unsigned int* __restrict__ rowinfo,
        const int* __restrict__ csrsrc4, unsigned short* __restrict__ agg0,
        int sbase, int fuseN) {
    int bx = blockIdx.x;
    int sl = bx % fuseN;                       // interleave snapshots across XCDs
    int rblk = bx / fuseN;
    int soff = (sbase + sl) * N_NODES;
    int wid = threadIdx.x >> 6;
    int lane = threadIdx.x & 63;
    int rA = (rblk << 3) + (wid << 1);         // 8 rows/block, 2 per wave
    int rB = rA + 1;
    const unsigned int* tp = (const unsigned int*)xb;   // 1 uint = 2 bf16; row = 64 uints
    const float* dv = dinv4 + soff;
    unsigned int riA = rowinfo[soff + rA];
    unsigned int riB = rowinfo[soff + rB];
    int eA = (int)(riA & 0xFFFFFFu), e1A = eA + (int)(riA >> 24);
    int eB = (int)(riB & 0xFFFFFFu), e1B = eB + (int)(riB >> 24);
    float diA = dv[rA], diB = dv[rB];
    float axA = 0.f, ayA = 0.f, axB = 0.f, ayB = 0.f;
    while (eA < e1A && eB < e1B) {             // dual-chain: loads overlap across A/B
        xbatch8(csrsrc4, eA, tp, dv, diA, lane, axA, ayA);
        xbatch8(csrsrc4, eB, tp, dv, diB, lane, axB, ayB);
        eA += 8; eB += 8;
    }
    while (eA < e1A) { xbatch8(csrsrc4, eA, tp, dv, diA, lane, axA, ayA); eA += 8; }
    while (eB < e1B) { xbatch8(csrsrc4, eB, tp, dv, diB, lane, axB, ayB); eB += 8; }
    unsigned int usA = tp[(size_t)rA * 64 + lane];      // self rows
    unsigned int usB = tp[(size_t)rB * 64 + lane];
    float wdA = diA * diA, wdB = diB * diB;
    axA = fmaf(bf2f((unsigned short)(usA & 0xffffu)), wdA, axA);
    ayA = fmaf(bf2f((unsigned short)(usA >> 16)),     wdA, ayA);
    axB = fmaf(bf2f((unsigned short)(usB & 0xffffu)), wdB, axB);
    ayB = fmaf(bf2f((unsigned short)(usB >> 16)),     wdB, ayB);
    unsigned int* outp = (unsigned int*)agg0 + (size_t)sl * N_NODES * 64;
    outp[(size_t)rA * 64 + lane] =
        (unsigned int)f2bf(axA) | ((unsigned int)f2bf(ayA) << 16);
    outp[(size_t)rB * 64 + lane] =
        (unsigned int)f2bf(axB) | ((unsigned int)f2bf(ayB) << 16);
}

// ------- MFMA GEMM per snapshot (r11-verified quadrant version): XCD-swizzled,
//         output restaged into the dead As tile, block-coalesced stores. -------
__global__ __launch_bounds__(256) void gemm_h_mfma(const unsigned short* __restrict__ A,
        const unsigned short* __restrict__ w1t, const float* __restrict__ b1,
        unsigned short* __restrict__ h, int M) {
    __shared__ unsigned short As[64][136];   // [m][k], +8 pad; reused as output stage
    __shared__ unsigned short Bs[64][136];   // [n][k]
    int i = blockIdx.x;
    int xcd = i & 7, j = i >> 3;
    int mg = xcd + ((j >> 2) << 3);          // same mg -> same XCD (assumes RR dispatch)
    int nq = j & 3;
    if (mg >= GH_MTILES) return;             // uniform early-exit (before barriers)
    int m0 = mg * 64, n0 = nq * 64;
    int tid = threadIdx.x;
    {
        int row = tid >> 2, c0 = (tid & 3) * 32;
        int gm = m0 + row;
        #pragma unroll
        for (int ii = 0; ii < 4; ++ii) {
            uint4 v = make_uint4(0u, 0u, 0u, 0u);
            if (gm < M) v = *(const uint4*)(A + (size_t)gm * D_IN + c0 + ii * 8);
            *(uint4*)&As[row][c0 + ii * 8] = v;
        }
    }
    {
        int n = tid >> 2, k0 = (tid & 3) * 32;
        #pragma unroll
        for (int ii = 0; ii < 4; ++ii) {
            *(uint4*)&Bs[n][k0 + ii * 8] =
                *(const uint4*)(w1t + (size_t)(n0 + n) * D_IN + k0 + ii * 8);
        }
    }
    __syncthreads();
    int w = tid >> 6, l = tid & 63;
    int q = l >> 4, mrow = l & 15;
    f32x4 acc[4] = {{0.f,0.f,0.f,0.f},{0.f,0.f,0.f,0.f},{0.f,0.f,0.f,0.f},{0.f,0.f,0.f,0.f}};
    #pragma unroll
    for (int kk = 0; kk < 4; ++kk) {
        bf16x8 a = *(const bf16x8*)&As[16 * w + mrow][kk * 32 + q * 8];
        #pragma unroll
        for (int ct = 0; ct < 4; ++ct) {
            bf16x8 b = *(const bf16x8*)&Bs[ct * 16 + mrow][kk * 32 + q * 8];
            acc[ct] = __builtin_amdgcn_mfma_f32_16x16x32_bf16(a, b, acc[ct], 0, 0, 0);
        }
    }
    // Restage output into As: wave w writes ONLY rows [16w,16w+16) — the same rows
    // only it read (acc data-dependency orders writes after all fragment reads).
    #pragma unroll
    for (int ct = 0; ct < 4; ++ct) {
        float bias = b1[n0 + ct * 16 + mrow];
        #pragma unroll
        for (int ii = 0; ii < 4; ++ii) {
            As[16 * w + q * 4 + ii][ct * 16 + mrow] =
                f2bf(fmaxf(acc[ct][ii] + bias, 0.f));
        }
    }
    __syncthreads();
    // Coalesced store: 64 rows x 128 B; 4 threads/row x 32 B contiguous runs.
    int row = tid >> 2, cc = (tid & 3) * 16;   // cc in shorts (32 B per thread)
    int m = m0 + row;
    if (m < M) {
        *(uint4*)&h[(size_t)m * H_DIM + n0 + cc]     = *(const uint4*)&As[row][cc];
        *(uint4*)&h[(size_t)m * H_DIM + n0 + cc + 8] = *(const uint4*)&As[row][cc + 8];
    }
}

// --- SpMM layer 1 (post rows), accumulating across snapshots; padded batches ---
__global__ __launch_bounds__(256) void spmm_h_post_kernel(const unsigned short* __restrict__ h,
        const float* __restrict__ dinv4, const unsigned int* __restrict__ rowinfo,
        const int* __restrict__ csrsrc4, const int* __restrict__ post,
        float* __restrict__ t1acc, float* __restrict__ hacc, int soff, int first) {
    int p = (blockIdx.x << 2) + (threadIdx.x >> 6);
    int lane = threadIdx.x & 63;
    int r = post[p];
    int rg = soff + r;
    unsigned int ri = rowinfo[rg];
    int e0 = (int)(ri & 0xFFFFFFu);
    int e1 = e0 + (int)(ri >> 24);
    float di = dinv4[rg];
    float4 acc = make_float4(0.f, 0.f, 0.f, 0.f);
    const ushort4* hp = (const ushort4*)h;
    const float* dv = dinv4 + soff;
    for (int e = e0; e + 8 <= e1; e += 8) {    // pdeg multiple of 8: exact coverage
        int4 q0 = *(const int4*)(csrsrc4 + e);
        int4 q1 = *(const int4*)(csrsrc4 + e + 4);
        int ss[8] = {q0.x, q0.y, q0.z, q0.w, q1.x, q1.y, q1.z, q1.w};
        float ww[8]; ushort4 uu[8];
        #pragma unroll
        for (int k = 0; k < 8; ++k) ww[k] = dv[ss[k]] * di;
        #pragma unroll
        for (int k = 0; k < 8; ++k) uu[k] = hp[(size_t)ss[k] * 64 + lane];
        #pragma unroll
        for (int k = 0; k < 8; ++k) {
            acc.x = fmaf(bf2f(uu[k].x), ww[k], acc.x);
            acc.y = fmaf(bf2f(uu[k].y), ww[k], acc.y);
            acc.z = fmaf(bf2f(uu[k].z), ww[k], acc.z);
            acc.w = fmaf(bf2f(uu[k].w), ww[k], acc.w);
        }
    }
    ushort4 u = hp[(size_t)r * 64 + lane];        // self row = h_s[post[p]]
    float hx = bf2f(u.x), hy = bf2f(u.y), hz = bf2f(u.z), hw = bf2f(u.w);
    float wd = di * di;
    acc.x = fmaf(hx, wd, acc.x);
    acc.y = fmaf(hy, wd, acc.y);
    acc.z = fmaf(hz, wd, acc.z);
    acc.w = fmaf(hw, wd, acc.w);
    size_t idx = (size_t)p * 64 + lane;
    float4 hv = make_float4(hx, hy, hz, hw);
    if (first) {
        ((float4*)t1acc)[idx] = acc;
        ((float4*)hacc)[idx] = hv;
    } else {
        float4 a = ((float4*)t1acc)[idx];
        a.x += acc.x; a.y += acc.y; a.z += acc.z; a.w += acc.w;
        ((float4*)t1acc)[idx] = a;
        float4 b = ((float4*)hacc)[idx];
        b.x += hv.x; b.y += hv.y; b.z += hv.z; b.w += hv.w;
        ((float4*)hacc)[idx] = b;
    }
}

// ------- MFMA GEMM layer 1 (ONCE): accP = t1acc @ W2 + 4*b2 + hacc -------
__global__ __launch_bounds__(256) void gemm_l1_mfma(const float* __restrict__ A,
        const unsigned short* __restrict__ w2t, const float* __restrict__ b2,
        const float* __restrict__ hacc, float* __restrict__ accP, int M) {
    __shared__ unsigned short As[64][136];
    __shared__ unsigned short Bs[64][136];
    int tid = threadIdx.x;
    int n0 = blockIdx.x * 64, m0 = blockIdx.y * 64;
    int w = tid >> 6, l = tid & 63;
    int q = l >> 4, mrow = l & 15;
    f32x4 acc[4] = {{0.f,0.f,0.f,0.f},{0.f,0.f,0.f,0.f},{0.f,0.f,0.f,0.f},{0.f,0.f,0.f,0.f}};
    for (int kk = 0; kk < 256; kk += 128) {
        __syncthreads();
        {
            int row = tid >> 2, c0 = (tid & 3) * 32;
            int gm = m0 + row;
            #pragma unroll
            for (int i = 0; i < 8; ++i) {
                float4 v = make_float4(0.f, 0.f, 0.f, 0.f);
                if (gm < M) v = *(const float4*)(A + (size_t)gm * 256 + kk + c0 + i * 4);
                As[row][c0 + i * 4 + 0] = f2bf(v.x);
                As[row][c0 + i * 4 + 1] = f2bf(v.y);
                As[row][c0 + i * 4 + 2] = f2bf(v.z);
                As[row][c0 + i * 4 + 3] = f2bf(v.w);
            }
        }
        {
            int n = tid >> 2, k0 = (tid & 3) * 32;
            #pragma unroll
            for (int i = 0; i < 4; ++i) {
                *(uint4*)&Bs[n][k0 + i * 8] =
                    *(const uint4*)(w2t + (size_t)(n0 + n) * H_DIM + kk + k0 + i * 8);
            }
        }
        __syncthreads();
        #pragma unroll
        for (int ks = 0; ks < 4; ++ks) {
            bf16x8 a = *(const bf16x8*)&As[16 * w + mrow][ks * 32 + q * 8];
            #pragma unroll
            for (int ct = 0; ct < 4; ++ct) {
                bf16x8 b = *(const bf16x8*)&Bs[ct * 16 + mrow][ks * 32 + q * 8];
                acc[ct] = __builtin_amdgcn_mfma_f32_16x16x32_bf16(a, b, acc[ct], 0, 0, 0);
            }
        }
    }
    #pragma unroll
    for (int ct = 0; ct < 4; ++ct) {
        int col = n0 + ct * 16 + mrow;
        float bias = 4.0f * b2[col];
        #pragma unroll
        for (int i = 0; i < 4; ++i) {
            int m = m0 + 16 * w + q * 4 + i;
            if (m < M) {
                accP[(size_t)m * 256 + col] =
                    acc[ct][i] + bias + hacc[(size_t)m * 256 + col];
            }
        }
    }
}

// ---------------- classifier ----------------
__global__ __launch_bounds__(128) void classifier_kernel(const float* __restrict__ accP,
        const float* __restrict__ Wc1, const float* __restrict__ bc1,
        const float* __restrict__ Wc2, const float* __restrict__ bc2,
        float* __restrict__ out) {
    __shared__ float arow[8][256];
    __shared__ float red[2][8];
    int p0 = blockIdx.x << 3;
    int tid = threadIdx.x;
    for (int idx = tid; idx < 8 * 256; idx += 128) {
        int pl = idx >> 8, k = idx & 255;
        arow[pl][k] = 0.25f * accP[(size_t)(p0 + pl) * 256 + k];
    }
    __syncthreads();
    float s[8];
    float b = bc1[tid];
    #pragma unroll
    for (int pl = 0; pl < 8; ++pl) s[pl] = b;
    for (int k = 0; k < 256; ++k) {
        float wv = Wc1[k * 128 + tid];
        #pragma unroll
        for (int pl = 0; pl < 8; ++pl) s[pl] = fmaf(arow[pl][k], wv, s[pl]);
    }
    float wc2 = Wc2[tid];
    float part[8];
    #pragma unroll
    for (int pl = 0; pl < 8; ++pl) part[pl] = fmaxf(s[pl], 0.f) * wc2;
    #pragma unroll
    for (int off = 32; off > 0; off >>= 1)
        #pragma unroll
        for (int pl = 0; pl < 8; ++pl) part[pl] += __shfl_down(part[pl], off, 64);
    int wave = tid >> 6, lane = tid & 63;
    if (lane == 0) {
        #pragma unroll
        for (int pl = 0; pl < 8; ++pl) red[wave][pl] = part[pl];
    }
    __syncthreads();
    if (tid < 8) {
        float logit = red[0][tid] + red[1][tid] + bc2[0];
        out[p0 + tid] = 1.f / (1.f + expf(-logit));
    }
}

extern "C" void kernel_launch(void* const* d_in, const int* in_sizes, int n_in,
                              void* d_out, int out_size, void* d_ws, size_t ws_size,
                              hipStream_t stream) {
    const float* x   = (const float*)d_in[0];
    const int*   ei  = (const int*)d_in[1];
    const int*   post= (const int*)d_in[2];
    const float* W1  = (const float*)d_in[3];
    const float* b1  = (const float*)d_in[4];
    const float* W2  = (const float*)d_in[5];
    const float* b2  = (const float*)d_in[6];
    const float* Wc1 = (const float*)d_in[7];
    const float* bc1 = (const float*)d_in[8];
    const float* Wc2 = (const float*)d_in[9];
    const float* bc2 = (const float*)d_in[10];
    float* out = (float*)d_out;

    // snapshot-fusion factor, chosen by available workspace (graceful fallback)
    const size_t NEED4 = 240000000ull;       // ~239.9 MB actual (r11 proved >=242 MB avail)
    const size_t NEED2 = 189000000ull;
    int fuseN = (ws_size >= NEED4) ? 4 : ((ws_size >= NEED2) ? 2 : 1);

    char* w = (char*)d_ws;
    size_t off = 0;
#define WS_ALLOC(type, name, count) \
    type* name = (type*)(w + off); \
    off += (((size_t)(count) * sizeof(type)) + 255) & ~(size_t)255;
    WS_ALLOC(unsigned short, xb,      (size_t)(N_NODES + 1) * D_IN)  // 25.6 MB (+zero row)
    WS_ALLOC(unsigned short, agg0,    (size_t)fuseN * N_NODES * D_IN) // 25.6*fuseN MB (accP aliases)
    WS_ALLOC(unsigned short, hbuf,    (size_t)(N_NODES + 1) * H_DIM) // 51.2 MB (+zero row; packed aliases)
    WS_ALLOC(float,          t1acc,   (size_t)P_POST * H_DIM)        // 10.24 MB
    WS_ALLOC(float,          hacc,    (size_t)P_POST * H_DIM)        // 10.24 MB
    WS_ALLOC(float,          dinv4,   N4 + 256)                      // 1.6 MB (+zero pad tail)
    WS_ALLOC(unsigned int,   rowinfo, N4)                            // 1.6 MB (ptr|pdeg<<24)
    WS_ALLOC(int,            csrsrc4, CSRSZ)                         // 36.8 MB (dense padded CSR)
    WS_ALLOC(int,            gcnt,    NPB)
    WS_ALLOC(int,            boffb,   NPB)
    WS_ALLOC(unsigned short, w1t,     (size_t)H_DIM * D_IN)          // 64 KB  W1^T bf16
    WS_ALLOC(unsigned short, w2t,     (size_t)H_DIM * H_DIM)         // 128 KB W2^T bf16
#undef WS_ALLOC
    // packed: NPB*CAPB u32 = 29.4 MB, aliases hbuf rows 0..57K — consumed by bucket_csr
    //   before any gemm_h writes h; hbuf zero-row (offset 51.2 MB) beyond packed.
    // accP [P,256] fp32 (10.24 MB) aliases agg0: agg0 dead after last gemm_h.
    unsigned int* packed = (unsigned int*)hbuf;
    float* accP = (float*)agg0;
    (void)in_sizes; (void)n_in; (void)out_size;

    // gcnt zero (memset), then: casts+padzero | single-pass scatter | scan | CSR build
    hipMemsetAsync(gcnt, 0, NPB * sizeof(int), stream);
    prep_kernel<<<PREP_GRID, 256, 0, stream>>>(x, W1, W2, xb, w1t, w2t, dinv4, hbuf);
    part_scatter_kernel<<<S_SNAP * NCHK, 256, 0, stream>>>(ei, gcnt, packed);
    scan_gcnt_kernel<<<1, 512, 0, stream>>>(gcnt, boffb);
    bucket_csr_kernel<<<NPB, 1024, 0, stream>>>(packed, gcnt, boffb, rowinfo, dinv4, csrsrc4);

    for (int g = 0; g < S_SNAP; g += fuseN) {
        // agg0[sl] = Ahat_{g+sl} @ Xbf16  — fuseN snapshots in ONE dispatch
        spmm_x_kernel<<<fuseN * (N_NODES / 8), 256, 0, stream>>>(
            xb, dinv4, rowinfo, csrsrc4, agg0, g, fuseN);
        for (int sl = 0; sl < fuseN; ++sl) {
            int s = g + sl;
            // h = relu(agg0[sl] @ W1 + b1)   [N,256] bf16  (XCD-swizzled quadrant MFMA)
            gemm_h_mfma<<<GH_GRID, 256, 0, stream>>>(
                agg0 + (size_t)sl * N_NODES * D_IN, w1t, b1, hbuf, N_NODES);
            // t1acc (+)= (Ahat @ h)[post];  hacc (+)= h[post]
            spmm_h_post_kernel<<<P_POST / 4, 256, 0, stream>>>(
                hbuf, dinv4, rowinfo, csrsrc4, post, t1acc, hacc, s * N_NODES, s == 0);
        }
    }
    // accP = t1acc @ W2 + 4*b2 + hacc   — single bf16 MFMA GEMM (W2 snapshot-invariant)
    dim3 g1(H_DIM / 64, (P_POST + 63) / 64);
    gemm_l1_mfma<<<g1, 256, 0, stream>>>(t1acc, w2t, b2, hacc, accP, P_POST);

    classifier_kernel<<<P_POST / 8, 128, 0, stream>>>(accP, Wc1, bc1, Wc2, bc2, out);
}

// Round 14
// 664.764 us; speedup vs baseline: 1.2078x; 1.0040x over previous
//
#include <hip/hip_runtime.h>
#include <math.h>

#define N_NODES 100000
#define E_EDGES 1600000
#define S_SNAP  4
#define D_IN    128
#define H_DIM   256
#define P_POST  10000
#define N4 (S_SNAP * N_NODES)               // 400000
#define E4 (S_SNAP * E_EDGES)               // 6400000

// ---- counting-sort graph prep (single-pass partition) ----
#define NBKT 128                             // coarse dst buckets per snapshot
#define BW_BKT 782                           // 128*782 = 100096 >= N_NODES
#define CHK 4096                             // edges per partition block
#define KPT (CHK / 256)                      // 16 edges per thread
#define NCHK ((E_EDGES + CHK - 1) / CHK)     // 391 chunks per snapshot
#define NPB (S_SNAP * NBKT)                  // 512 (snapshot,bucket) units
#define CAPB 14336                           // fixed packed capacity/bucket (16sigma slack)
#define CSR_CAP 14336                        // LDS staging cap in bucket_csr
#define PADCAP 5480                          // per-bucket pad slack: 7*782=5474 worst +align
#define CSRSZ (E4 + NPB * PADCAP + 8)        // 9,205,768 < 2^24 (dense padded CSR)

// ---- prep kernel block ranges: xb cast | w cast | pad-zero | gcnt-zero ----
#define CAST_XBLK (N_NODES * D_IN / 4 / 256)                  // 12500
#define CAST_WBLK ((D_IN * H_DIM + H_DIM * H_DIM) / 256)      // 384
#define PREP_PZ   (CAST_XBLK + CAST_WBLK)                     // pad-zero block
#define PREP_GRID (PREP_PZ + 1 + 2)                           // +2 gcnt-zero blocks

// ---- gemm_h XCD swizzle (r11-verified quadrant version) ----
#define GH_MTILES ((N_NODES + 63) / 64)      // 1563
#define GH_GRID   6272                       // 8 XCD * 784; maps mg<=1567, 20 blocks idle

typedef __attribute__((ext_vector_type(8))) short bf16x8;   // MFMA A/B frag (4 VGPRs)
typedef __attribute__((ext_vector_type(4))) float f32x4;    // MFMA C/D frag

// ---------- bf16 helpers ----------
__device__ __forceinline__ float bf2f(unsigned short u) {
    union { unsigned int i; float f; } v; v.i = ((unsigned int)u) << 16; return v.f;
}
__device__ __forceinline__ unsigned short f2bf(float f) {
    union { float f; unsigned int i; } v; v.f = f;
    unsigned int lsb = (v.i >> 16) & 1u;
    v.i += 0x7fffu + lsb;                 // round-nearest-even
    return (unsigned short)(v.i >> 16);
}

// ---- prep: X cast + W transpose-cast + pad-row zero + gcnt zero ----
__global__ __launch_bounds__(256) void prep_kernel(const float* __restrict__ x,
        const float* __restrict__ W1, const float* __restrict__ W2,
        unsigned short* __restrict__ xb, unsigned short* __restrict__ w1t,
        unsigned short* __restrict__ w2t, float* __restrict__ dinv4,
        unsigned short* __restrict__ hbuf, int* __restrict__ gcnt) {
    int bx = blockIdx.x;
    int t = threadIdx.x;
    if (bx < CAST_XBLK) {
        int i = bx * 256 + t;                // over N*D/4 float4 groups
        float4 v = ((const float4*)x)[i];
        ushort4 o;
        o.x = f2bf(v.x); o.y = f2bf(v.y); o.z = f2bf(v.z); o.w = f2bf(v.w);
        ((ushort4*)xb)[i] = o;
    } else if (bx < PREP_PZ) {
        int i = (bx - CAST_XBLK) * 256 + t;
        if (i < D_IN * H_DIM) {              // w1t[n][k] = W1[k][n]
            int k = i >> 8, n = i & 255;
            w1t[n * D_IN + k] = f2bf(W1[i]);
        } else {                             // w2t[n][k] = W2[k][n]
            int j = i - D_IN * H_DIM;
            int k = j >> 8, n = j & 255;
            w2t[n * H_DIM + k] = f2bf(W2[j]);
        }
    } else if (bx == PREP_PZ) {
        // pad-row zeroing: dinv4 tail (pad weight), xb row N, hbuf row N
        dinv4[N4 + t] = 0.f;                                  // 256 floats
        if (t < 64)  ((unsigned int*)xb)[(size_t)N_NODES * 64 + t] = 0u;    // 128 bf16
        if (t < 128) ((unsigned int*)hbuf)[(size_t)N_NODES * 128 + t] = 0u; // 256 bf16
    } else {
        int i = (bx - PREP_PZ - 1) * 256 + t;                 // 512 gcnt ints
        if (i < NPB) gcnt[i] = 0;
    }
}

// ---- SINGLE-PASS partition: LDS-count + direct atomic reservation into
//      fixed-capacity bucket regions of `packed`. ----
__global__ __launch_bounds__(256) void part_scatter_kernel(const int* __restrict__ ei,
        int* __restrict__ gcnt, unsigned int* __restrict__ packed) {
    __shared__ int cnt[NBKT];
    __shared__ int sco[NBKT];
    __shared__ int lofs[NBKT + 1];
    __shared__ int cb2[NBKT];
    __shared__ unsigned int lbuf[CHK];         // 16 KB staging
    __shared__ unsigned char bbuf[CHK];        // 4 KB bucket ids
    int bx = blockIdx.x;
    int s = bx / NCHK, c = bx - s * NCHK;
    int t = threadIdx.x;
    if (t < NBKT) cnt[t] = 0;
    __syncthreads();
    const int* srcp = ei + (size_t)s * 2 * E_EDGES;
    const int* dstp = srcp + E_EDGES;
    int base = c * CHK + t;
    unsigned int pv[KPT];
    int prb[KPT];                              // (bucket<<13) | rank  (rank < 4096)
    #pragma unroll
    for (int k = 0; k < KPT; ++k) {
        int j = base + k * 256;
        prb[k] = -1;
        if (j < E_EDGES) {
            int d = dstp[j];
            int b = d / BW_BKT;
            int dl = d - b * BW_BKT;           // < 782 -> 10 bits; src < 2^17
            pv[k] = (unsigned int)srcp[j] | ((unsigned int)dl << 17);
            int r = atomicAdd(&cnt[b], 1);     // LDS atomic
            prb[k] = (b << 13) | r;
        }
    }
    __syncthreads();
    if (t < NBKT) sco[t] = cnt[t];
    __syncthreads();
    for (int off = 1; off < NBKT; off <<= 1) { // exclusive scan over 128 counters
        int u = (t < NBKT && t >= off) ? sco[t - off] : 0;
        __syncthreads();
        if (t < NBKT) sco[t] += u;
        __syncthreads();
    }
    if (t < NBKT) {
        int ex = sco[t] - cnt[t];
        lofs[t] = ex;
        if (t == NBKT - 1) lofs[NBKT] = sco[t];
        // direct reservation: base within this bucket's fixed region
        int rbase = atomicAdd(&gcnt[s * NBKT + t], cnt[t]);
        cb2[t] = (s * NBKT + t) * CAPB + rbase - ex;
    }
    __syncthreads();
    #pragma unroll
    for (int k = 0; k < KPT; ++k) {
        if (prb[k] >= 0) {
            int b = prb[k] >> 13;
            int pos = lofs[b] + (prb[k] & 0x1FFF);
            lbuf[pos] = pv[k];
            bbuf[pos] = (unsigned char)b;
        }
    }
    __syncthreads();
    int tot = lofs[NBKT];
    for (int i = t; i < tot; i += 256) {       // consecutive i -> coalesced bucket runs
        packed[cb2[bbuf[i]] + i] = lbuf[i];
    }
}

// ---- pass 2: per-(snapshot,bucket) CSR build; packed read from FIXED region,
//      csrsrc written densely. Inline prefix over gcnt (scan_gcnt folded in). ----
__global__ __launch_bounds__(1024) void bucket_csr_kernel(const unsigned int* __restrict__ packed,
        const int* __restrict__ gcnt, unsigned int* __restrict__ rowinfo,
        float* __restrict__ dinv4, int* __restrict__ csrsrc4) {
    __shared__ int deg[BW_BKT];                // histogram, then cursor
    __shared__ int sc[1024];
    __shared__ unsigned int stg[CSR_CAP];      // 56 KB edge staging
    __shared__ int sEbase;
    int bx = blockIdx.x;                       // s*NBKT + b
    int s = bx >> 7, b = bx & (NBKT - 1);
    int t = threadIdx.x;
    // inline exclusive prefix: ebase = sum gcnt[0..bx)
    sc[t] = (t < bx) ? gcnt[t] : 0;            // bx < NPB=512 so t<bx implies valid
    __syncthreads();
    for (int off = 1; off < 1024; off <<= 1) {
        int u = (t >= off) ? sc[t - off] : 0;
        __syncthreads();
        sc[t] += u;
        __syncthreads();
    }
    if (t == 1023) sEbase = sc[1023];
    for (int i = t; i < BW_BKT; i += 1024) deg[i] = 0;
    __syncthreads();
    int ebase = sEbase;                        // dense (unpadded) running offset
    int pbase = ((ebase + 3) & ~3) + bx * PADCAP;  // csrsrc4 (padded, 16B-aligned rows)
    int ecnt = gcnt[bx];
    bool fits = (ecnt <= CSR_CAP);
    const unsigned int* pk = packed + (size_t)bx * CAPB;   // fixed-capacity region
    if (fits) {
        for (int i = t; i < ecnt; i += 1024) {
            unsigned int p = pk[i];
            stg[i] = p;
            atomicAdd(&deg[p >> 17], 1);       // LDS atomic
        }
    } else {
        for (int i = t; i < ecnt; i += 1024) atomicAdd(&deg[pk[i] >> 17], 1);
    }
    __syncthreads();
    int d0 = (t < BW_BKT) ? deg[t] : 0;
    int pd = (d0 + 7) & ~7;                    // pad to multiple of 8
    sc[t] = pd;
    __syncthreads();
    for (int off = 1; off < 1024; off <<= 1) {
        int u = (t >= off) ? sc[t - off] : 0;
        __syncthreads();
        sc[t] += u;
        __syncthreads();
    }
    int pex = sc[t] - pd;                      // padded exclusive within bucket
    int g = b * BW_BKT + t;
    if (t < BW_BKT && g < N_NODES) {
        rowinfo[s * N_NODES + g] =
            (unsigned int)(pbase + pex) | ((unsigned int)pd << 24);
        dinv4[s * N_NODES + g] = rsqrtf((float)(d0 + 1));   // +1 self-loop
        for (int i = d0; i < pd; ++i) csrsrc4[pbase + pex + i] = N_NODES;  // pad slots
    }
    __syncthreads();
    if (t < BW_BKT) deg[t] = pex;              // becomes cursor (padded offsets)
    __syncthreads();
    if (fits) {
        for (int i = t; i < ecnt; i += 1024) {
            unsigned int p = stg[i];
            int r = atomicAdd(&deg[p >> 17], 1);   // LDS atomic, unique slot per dst
            csrsrc4[pbase + r] = (int)(p & 0x1FFFFu);
        }
    } else {
        for (int i = t; i < ecnt; i += 1024) {
            unsigned int p = pk[i];
            int r = atomicAdd(&deg[p >> 17], 1);
            csrsrc4[pbase + r] = (int)(p & 0x1FFFFu);
        }
    }
}

// ---- one 8-edge batch for the feature aggregation (2 bf16/lane rows) ----
__device__ __forceinline__ void xbatch8(const int* __restrict__ csrsrc4, int e,
        const unsigned int* __restrict__ tp, const float* __restrict__ dv,
        float di, int lane, float& ax, float& ay) {
    int4 q0 = *(const int4*)(csrsrc4 + e);
    int4 q1 = *(const int4*)(csrsrc4 + e + 4);
    float w0 = dv[q0.x] * di, w1 = dv[q0.y] * di, w2 = dv[q0.z] * di, w3 = dv[q0.w] * di;
    float w4 = dv[q1.x] * di, w5 = dv[q1.y] * di, w6 = dv[q1.z] * di, w7 = dv[q1.w] * di;
    unsigned int u0 = tp[(size_t)q0.x * 64 + lane];
    unsigned int u1 = tp[(size_t)q0.y * 64 + lane];
    unsigned int u2 = tp[(size_t)q0.z * 64 + lane];
    unsigned int u3 = tp[(size_t)q0.w * 64 + lane];
    unsigned int u4 = tp[(size_t)q1.x * 64 + lane];
    unsigned int u5 = tp[(size_t)q1.y * 64 + lane];
    unsigned int u6 = tp[(size_t)q1.z * 64 + lane];
    unsigned int u7 = tp[(size_t)q1.w * 64 + lane];
    ax = fmaf(bf2f((unsigned short)(u0 & 0xffffu)), w0, ax);
    ay = fmaf(bf2f((unsigned short)(u0 >> 16)),     w0, ay);
    ax = fmaf(bf2f((unsigned short)(u1 & 0xffffu)), w1, ax);
    ay = fmaf(bf2f((unsigned short)(u1 >> 16)),     w1, ay);
    ax = fmaf(bf2f((unsigned short)(u2 & 0xffffu)), w2, ax);
    ay = fmaf(bf2f((unsigned short)(u2 >> 16)),     w2, ay);
    ax = fmaf(bf2f((unsigned short)(u3 & 0xffffu)), w3, ax);
    ay = fmaf(bf2f((unsigned short)(u3 >> 16)),     w3, ay);
    ax = fmaf(bf2f((unsigned short)(u4 & 0xffffu)), w4, ax);
    ay = fmaf(bf2f((unsigned short)(u4 >> 16)),     w4, ay);
    ax = fmaf(bf2f((unsigned short)(u5 & 0xffffu)), w5, ax);
    ay = fmaf(bf2f((unsigned short)(u5 >> 16)),     w5, ay);
    ax = fmaf(bf2f((unsigned short)(u6 & 0xffffu)), w6, ax);
    ay = fmaf(bf2f((unsigned short)(u6 >> 16)),     w6, ay);
    ax = fmaf(bf2f((unsigned short)(u7 & 0xffffu)), w7, ax);
    ay = fmaf(bf2f((unsigned short)(u7 >> 16)),     w7, ay);
}

// ---- one 8-edge batch for the h aggregation (ushort4 = 4 bf16/lane) ----
__device__ __forceinline__ void hbatch8(const int* __restrict__ csrsrc4, int e,
        const ushort4* __restrict__ hp, const float* __restrict__ dv,
        float di, int lane, float4& acc) {
    int4 q0 = *(const int4*)(csrsrc4 + e);
    int4 q1 = *(const int4*)(csrsrc4 + e + 4);
    int ss[8] = {q0.x, q0.y, q0.z, q0.w, q1.x, q1.y, q1.z, q1.w};
    float ww[8]; ushort4 uu[8];
    #pragma unroll
    for (int k = 0; k < 8; ++k) ww[k] = dv[ss[k]] * di;
    #pragma unroll
    for (int k = 0; k < 8; ++k) uu[k] = hp[(size_t)ss[k] * 64 + lane];
    #pragma unroll
    for (int k = 0; k < 8; ++k) {
        acc.x = fmaf(bf2f(uu[k].x), ww[k], acc.x);
        acc.y = fmaf(bf2f(uu[k].y), ww[k], acc.y);
        acc.z = fmaf(bf2f(uu[k].z), ww[k], acc.z);
        acc.w = fmaf(bf2f(uu[k].w), ww[k], acc.w);
    }
}

// ------- SpMM layer 0, SNAPSHOT-FUSED (r11-verified) -------
__global__ __launch_bounds__(256) void spmm_x_kernel(const unsigned short* __restrict__ xb,
        const float* __restrict__ dinv4, const unsigned int* __restrict__ rowinfo,
        const int* __restrict__ csrsrc4, unsigned short* __restrict__ agg0,
        int sbase, int fuseN) {
    int bx = blockIdx.x;
    int sl = bx % fuseN;                       // interleave snapshots across XCDs
    int rblk = bx / fuseN;
    int soff = (sbase + sl) * N_NODES;
    int wid = threadIdx.x >> 6;
    int lane = threadIdx.x & 63;
    int rA = (rblk << 3) + (wid << 1);         // 8 rows/block, 2 per wave
    int rB = rA + 1;
    const unsigned int* tp = (const unsigned int*)xb;   // 1 uint = 2 bf16; row = 64 uints
    const float* dv = dinv4 + soff;
    unsigned int riA = rowinfo[soff + rA];
    unsigned int riB = rowinfo[soff + rB];
    int eA = (int)(riA & 0xFFFFFFu), e1A = eA + (int)(riA >> 24);
    int eB = (int)(riB & 0xFFFFFFu), e1B = eB + (int)(riB >> 24);
    float diA = dv[rA], diB = dv[rB];
    float axA = 0.f, ayA = 0.f, axB = 0.f, ayB = 0.f;
    while (eA < e1A && eB < e1B) {             // dual-chain: loads overlap across A/B
        xbatch8(csrsrc4, eA, tp, dv, diA, lane, axA, ayA);
        xbatch8(csrsrc4, eB, tp, dv, diB, lane, axB, ayB);
        eA += 8; eB += 8;
    }
    while (eA < e1A) { xbatch8(csrsrc4, eA, tp, dv, diA, lane, axA, ayA); eA += 8; }
    while (eB < e1B) { xbatch8(csrsrc4, eB, tp, dv, diB, lane, axB, ayB); eB += 8; }
    unsigned int usA = tp[(size_t)rA * 64 + lane];      // self rows
    unsigned int usB = tp[(size_t)rB * 64 + lane];
    float wdA = diA * diA, wdB = diB * diB;
    axA = fmaf(bf2f((unsigned short)(usA & 0xffffu)), wdA, axA);
    ayA = fmaf(bf2f((unsigned short)(usA >> 16)),     wdA, ayA);
    axB = fmaf(bf2f((unsigned short)(usB & 0xffffu)), wdB, axB);
    ayB = fmaf(bf2f((unsigned short)(usB >> 16)),     wdB, ayB);
    unsigned int* outp = (unsigned int*)agg0 + (size_t)sl * N_NODES * 64;
    outp[(size_t)rA * 64 + lane] =
        (unsigned int)f2bf(axA) | ((unsigned int)f2bf(ayA) << 16);
    outp[(size_t)rB * 64 + lane] =
        (unsigned int)f2bf(axB) | ((unsigned int)f2bf(ayB) << 16);
}

// ------- MFMA GEMM per snapshot (r11-verified quadrant version) -------
__global__ __launch_bounds__(256) void gemm_h_mfma(const unsigned short* __restrict__ A,
        const unsigned short* __restrict__ w1t, const float* __restrict__ b1,
        unsigned short* __restrict__ h, int M) {
    __shared__ unsigned short As[64][136];   // [m][k], +8 pad; reused as output stage
    __shared__ unsigned short Bs[64][136];   // [n][k]
    int i = blockIdx.x;
    int xcd = i & 7, j = i >> 3;
    int mg = xcd + ((j >> 2) << 3);          // same mg -> same XCD (assumes RR dispatch)
    int nq = j & 3;
    if (mg >= GH_MTILES) return;             // uniform early-exit (before barriers)
    int m0 = mg * 64, n0 = nq * 64;
    int tid = threadIdx.x;
    {
        int row = tid >> 2, c0 = (tid & 3) * 32;
        int gm = m0 + row;
        #pragma unroll
        for (int ii = 0; ii < 4; ++ii) {
            uint4 v = make_uint4(0u, 0u, 0u, 0u);
            if (gm < M) v = *(const uint4*)(A + (size_t)gm * D_IN + c0 + ii * 8);
            *(uint4*)&As[row][c0 + ii * 8] = v;
        }
    }
    {
        int n = tid >> 2, k0 = (tid & 3) * 32;
        #pragma unroll
        for (int ii = 0; ii < 4; ++ii) {
            *(uint4*)&Bs[n][k0 + ii * 8] =
                *(const uint4*)(w1t + (size_t)(n0 + n) * D_IN + k0 + ii * 8);
        }
    }
    __syncthreads();
    int w = tid >> 6, l = tid & 63;
    int q = l >> 4, mrow = l & 15;
    f32x4 acc[4] = {{0.f,0.f,0.f,0.f},{0.f,0.f,0.f,0.f},{0.f,0.f,0.f,0.f},{0.f,0.f,0.f,0.f}};
    #pragma unroll
    for (int kk = 0; kk < 4; ++kk) {
        bf16x8 a = *(const bf16x8*)&As[16 * w + mrow][kk * 32 + q * 8];
        #pragma unroll
        for (int ct = 0; ct < 4; ++ct) {
            bf16x8 b = *(const bf16x8*)&Bs[ct * 16 + mrow][kk * 32 + q * 8];
            acc[ct] = __builtin_amdgcn_mfma_f32_16x16x32_bf16(a, b, acc[ct], 0, 0, 0);
        }
    }
    // Restage output into As: wave w writes ONLY rows [16w,16w+16)
    #pragma unroll
    for (int ct = 0; ct < 4; ++ct) {
        float bias = b1[n0 + ct * 16 + mrow];
        #pragma unroll
        for (int ii = 0; ii < 4; ++ii) {
            As[16 * w + q * 4 + ii][ct * 16 + mrow] =
                f2bf(fmaxf(acc[ct][ii] + bias, 0.f));
        }
    }
    __syncthreads();
    // Coalesced store: 64 rows x 128 B; 4 threads/row x 32 B contiguous runs.
    int row = tid >> 2, cc = (tid & 3) * 16;   // cc in shorts (32 B per thread)
    int m = m0 + row;
    if (m < M) {
        *(uint4*)&h[(size_t)m * H_DIM + n0 + cc]     = *(const uint4*)&As[row][cc];
        *(uint4*)&h[(size_t)m * H_DIM + n0 + cc + 8] = *(const uint4*)&As[row][cc + 8];
    }
}

// --- SpMM layer 1 (post rows), DUAL-ROW waves (r5-verified idiom):
//     2 posts/wave, interleaved 8-batches -> 2x memory-level parallelism. ---
__global__ __launch_bounds__(256) void spmm_h_post_kernel(const unsigned short* __restrict__ h,
        const float* __restrict__ dinv4, const unsigned int* __restrict__ rowinfo,
        const int* __restrict__ csrsrc4, const int* __restrict__ post,
        float* __restrict__ t1acc, float* __restrict__ hacc, int soff, int first) {
    int wid = threadIdx.x >> 6;
    int lane = threadIdx.x & 63;
    int pA = (blockIdx.x << 3) + (wid << 1);   // 8 posts/block, 2 per wave
    int pB = pA + 1;
    int rA = post[pA], rB = post[pB];
    const ushort4* hp = (const ushort4*)h;
    const float* dv = dinv4 + soff;
    unsigned int riA = rowinfo[soff + rA];
    unsigned int riB = rowinfo[soff + rB];
    int eA = (int)(riA & 0xFFFFFFu), e1A = eA + (int)(riA >> 24);
    int eB = (int)(riB & 0xFFFFFFu), e1B = eB + (int)(riB >> 24);
    float diA = dv[rA], diB = dv[rB];
    float4 accA = make_float4(0.f, 0.f, 0.f, 0.f);
    float4 accB = make_float4(0.f, 0.f, 0.f, 0.f);
    while (eA < e1A && eB < e1B) {
        hbatch8(csrsrc4, eA, hp, dv, diA, lane, accA);
        hbatch8(csrsrc4, eB, hp, dv, diB, lane, accB);
        eA += 8; eB += 8;
    }
    while (eA < e1A) { hbatch8(csrsrc4, eA, hp, dv, diA, lane, accA); eA += 8; }
    while (eB < e1B) { hbatch8(csrsrc4, eB, hp, dv, diB, lane, accB); eB += 8; }
    ushort4 uA = hp[(size_t)rA * 64 + lane];      // self rows = h_s[post]
    ushort4 uB = hp[(size_t)rB * 64 + lane];
    float hxA = bf2f(uA.x), hyA = bf2f(uA.y), hzA = bf2f(uA.z), hwA = bf2f(uA.w);
    float hxB = bf2f(uB.x), hyB = bf2f(uB.y), hzB = bf2f(uB.z), hwB = bf2f(uB.w);
    float wdA = diA * diA, wdB = diB * diB;
    accA.x = fmaf(hxA, wdA, accA.x); accA.y = fmaf(hyA, wdA, accA.y);
    accA.z = fmaf(hzA, wdA, accA.z); accA.w = fmaf(hwA, wdA, accA.w);
    accB.x = fmaf(hxB, wdB, accB.x); accB.y = fmaf(hyB, wdB, accB.y);
    accB.z = fmaf(hzB, wdB, accB.z); accB.w = fmaf(hwB, wdB, accB.w);
    size_t idxA = (size_t)pA * 64 + lane;
    size_t idxB = (size_t)pB * 64 + lane;
    float4 hvA = make_float4(hxA, hyA, hzA, hwA);
    float4 hvB = make_float4(hxB, hyB, hzB, hwB);
    if (first) {
        ((float4*)t1acc)[idxA] = accA;
        ((float4*)t1acc)[idxB] = accB;
        ((float4*)hacc)[idxA] = hvA;
        ((float4*)hacc)[idxB] = hvB;
    } else {
        float4 a = ((float4*)t1acc)[idxA];
        a.x += accA.x; a.y += accA.y; a.z += accA.z; a.w += accA.w;
        ((float4*)t1acc)[idxA] = a;
        float4 b = ((float4*)t1acc)[idxB];
        b.x += accB.x; b.y += accB.y; b.z += accB.z; b.w += accB.w;
        ((float4*)t1acc)[idxB] = b;
        float4 c = ((float4*)hacc)[idxA];
        c.x += hvA.x; c.y += hvA.y; c.z += hvA.z; c.w += hvA.w;
        ((float4*)hacc)[idxA] = c;
        float4 d = ((float4*)hacc)[idxB];
        d.x += hvB.x; d.y += hvB.y; d.z += hvB.z; d.w += hvB.w;
        ((float4*)hacc)[idxB] = d;
    }
}

// ------- MFMA GEMM layer 1 (ONCE): accP = t1acc @ W2 + 4*b2 + hacc -------
__global__ __launch_bounds__(256) void gemm_l1_mfma(const float* __restrict__ A,
        const unsigned short* __restrict__ w2t, const float* __restrict__ b2,
        const float* __restrict__ hacc, float* __restrict__ accP, int M) {
    __shared__ unsigned short As[64][136];
    __shared__ unsigned short Bs[64][136];
    int tid = threadIdx.x;
    int n0 = blockIdx.x * 64, m0 = blockIdx.y * 64;
    int w = tid >> 6, l = tid & 63;
    int q = l >> 4, mrow = l & 15;
    f32x4 acc[4] = {{0.f,0.f,0.f,0.f},{0.f,0.f,0.f,0.f},{0.f,0.f,0.f,0.f},{0.f,0.f,0.f,0.f}};
    for (int kk = 0; kk < 256; kk += 128) {
        __syncthreads();
        {
            int row = tid >> 2, c0 = (tid & 3) * 32;
            int gm = m0 + row;
            #pragma unroll
            for (int i = 0; i < 8; ++i) {
                float4 v = make_float4(0.f, 0.f, 0.f, 0.f);
                if (gm < M) v = *(const float4*)(A + (size_t)gm * 256 + kk + c0 + i * 4);
                As[row][c0 + i * 4 + 0] = f2bf(v.x);
                As[row][c0 + i * 4 + 1] = f2bf(v.y);
                As[row][c0 + i * 4 + 2] = f2bf(v.z);
                As[row][c0 + i * 4 + 3] = f2bf(v.w);
            }
        }
        {
            int n = tid >> 2, k0 = (tid & 3) * 32;
            #pragma unroll
            for (int i = 0; i < 4; ++i) {
                *(uint4*)&Bs[n][k0 + i * 8] =
                    *(const uint4*)(w2t + (size_t)(n0 + n) * H_DIM + kk + k0 + i * 8);
            }
        }
        __syncthreads();
        #pragma unroll
        for (int ks = 0; ks < 4; ++ks) {
            bf16x8 a = *(const bf16x8*)&As[16 * w + mrow][ks * 32 + q * 8];
            #pragma unroll
            for (int ct = 0; ct < 4; ++ct) {
                bf16x8 b = *(const bf16x8*)&Bs[ct * 16 + mrow][ks * 32 + q * 8];
                acc[ct] = __builtin_amdgcn_mfma_f32_16x16x32_bf16(a, b, acc[ct], 0, 0, 0);
            }
        }
    }
    #pragma unroll
    for (int ct = 0; ct < 4; ++ct) {
        int col = n0 + ct * 16 + mrow;
        float bias = 4.0f * b2[col];
        #pragma unroll
        for (int i = 0; i < 4; ++i) {
            int m = m0 + 16 * w + q * 4 + i;
            if (m < M) {
                accP[(size_t)m * 256 + col] =
                    acc[ct][i] + bias + hacc[(size_t)m * 256 + col];
            }
        }
    }
}

// ---------------- classifier ----------------
__global__ __launch_bounds__(128) void classifier_kernel(const float* __restrict__ accP,
        const float* __restrict__ Wc1, const float* __restrict__ bc1,
        const float* __restrict__ Wc2, const float* __restrict__ bc2,
        float* __restrict__ out) {
    __shared__ float arow[8][256];
    __shared__ float red[2][8];
    int p0 = blockIdx.x << 3;
    int tid = threadIdx.x;
    for (int idx = tid; idx < 8 * 256; idx += 128) {
        int pl = idx >> 8, k = idx & 255;
        arow[pl][k] = 0.25f * accP[(size_t)(p0 + pl) * 256 + k];
    }
    __syncthreads();
    float s[8];
    float b = bc1[tid];
    #pragma unroll
    for (int pl = 0; pl < 8; ++pl) s[pl] = b;
    for (int k = 0; k < 256; ++k) {
        float wv = Wc1[k * 128 + tid];
        #pragma unroll
        for (int pl = 0; pl < 8; ++pl) s[pl] = fmaf(arow[pl][k], wv, s[pl]);
    }
    float wc2 = Wc2[tid];
    float part[8];
    #pragma unroll
    for (int pl = 0; pl < 8; ++pl) part[pl] = fmaxf(s[pl], 0.f) * wc2;
    #pragma unroll
    for (int off = 32; off > 0; off >>= 1)
        #pragma unroll
        for (int pl = 0; pl < 8; ++pl) part[pl] += __shfl_down(part[pl], off, 64);
    int wave = tid >> 6, lane = tid & 63;
    if (lane == 0) {
        #pragma unroll
        for (int pl = 0; pl < 8; ++pl) red[wave][pl] = part[pl];
    }
    __syncthreads();
    if (tid < 8) {
        float logit = red[0][tid] + red[1][tid] + bc2[0];
        out[p0 + tid] = 1.f / (1.f + expf(-logit));
    }
}

extern "C" void kernel_launch(void* const* d_in, const int* in_sizes, int n_in,
                              void* d_out, int out_size, void* d_ws, size_t ws_size,
                              hipStream_t stream) {
    const float* x   = (const float*)d_in[0];
    const int*   ei  = (const int*)d_in[1];
    const int*   post= (const int*)d_in[2];
    const float* W1  = (const float*)d_in[3];
    const float* b1  = (const float*)d_in[4];
    const float* W2  = (const float*)d_in[5];
    const float* b2  = (const float*)d_in[6];
    const float* Wc1 = (const float*)d_in[7];
    const float* bc1 = (const float*)d_in[8];
    const float* Wc2 = (const float*)d_in[9];
    const float* bc2 = (const float*)d_in[10];
    float* out = (float*)d_out;

    // snapshot-fusion factor, chosen by available workspace (graceful fallback)
    const size_t NEED4 = 240000000ull;
    const size_t NEED2 = 189000000ull;
    int fuseN = (ws_size >= NEED4) ? 4 : ((ws_size >= NEED2) ? 2 : 1);

    char* w = (char*)d_ws;
    size_t off = 0;
#define WS_ALLOC(type, name, count) \
    type* name = (type*)(w + off); \
    off += (((size_t)(count) * sizeof(type)) + 255) & ~(size_t)255;
    WS_ALLOC(unsigned short, xb,      (size_t)(N_NODES + 1) * D_IN)  // 25.6 MB (+zero row)
    WS_ALLOC(unsigned short, agg0,    (size_t)fuseN * N_NODES * D_IN) // 25.6*fuseN MB (accP aliases)
    WS_ALLOC(unsigned short, hbuf,    (size_t)(N_NODES + 1) * H_DIM) // 51.2 MB (+zero row; packed aliases)
    WS_ALLOC(float,          t1acc,   (size_t)P_POST * H_DIM)        // 10.24 MB
    WS_ALLOC(float,          hacc,    (size_t)P_POST * H_DIM)        // 10.24 MB
    WS_ALLOC(float,          dinv4,   N4 + 256)                      // 1.6 MB (+zero pad tail)
    WS_ALLOC(unsigned int,   rowinfo, N4)                            // 1.6 MB (ptr|pdeg<<24)
    WS_ALLOC(int,            csrsrc4, CSRSZ)                         // 36.8 MB (dense padded CSR)
    WS_ALLOC(int,            gcnt,    NPB)
    WS_ALLOC(unsigned short, w1t,     (size_t)H_DIM * D_IN)          // 64 KB  W1^T bf16
    WS_ALLOC(unsigned short, w2t,     (size_t)H_DIM * H_DIM)         // 128 KB W2^T bf16
#undef WS_ALLOC
    // packed: NPB*CAPB u32 = 29.4 MB, aliases hbuf rows 0..57K — consumed by bucket_csr
    //   before any gemm_h writes h; hbuf zero-row (offset 51.2 MB) beyond packed.
    // accP [P,256] fp32 (10.24 MB) aliases agg0: agg0 dead after last gemm_h.
    unsigned int* packed = (unsigned int*)hbuf;
    float* accP = (float*)agg0;
    (void)in_sizes; (void)n_in; (void)out_size;

    // prep: casts + pad-zero + gcnt-zero | single-pass scatter | CSR build (scan folded)
    prep_kernel<<<PREP_GRID, 256, 0, stream>>>(x, W1, W2, xb, w1t, w2t, dinv4, hbuf, gcnt);
    part_scatter_kernel<<<S_SNAP * NCHK, 256, 0, stream>>>(ei, gcnt, packed);
    bucket_csr_kernel<<<NPB, 1024, 0, stream>>>(packed, gcnt, rowinfo, dinv4, csrsrc4);

    for (int g = 0; g < S_SNAP; g += fuseN) {
        // agg0[sl] = Ahat_{g+sl} @ Xbf16  — fuseN snapshots in ONE dispatch
        spmm_x_kernel<<<fuseN * (N_NODES / 8), 256, 0, stream>>>(
            xb, dinv4, rowinfo, csrsrc4, agg0, g, fuseN);
        for (int sl = 0; sl < fuseN; ++sl) {
            int s = g + sl;
            // h = relu(agg0[sl] @ W1 + b1)   [N,256] bf16  (XCD-swizzled quadrant MFMA)
            gemm_h_mfma<<<GH_GRID, 256, 0, stream>>>(
                agg0 + (size_t)sl * N_NODES * D_IN, w1t, b1, hbuf, N_NODES);
            // t1acc (+)= (Ahat @ h)[post];  hacc (+)= h[post]  (dual-row waves)
            spmm_h_post_kernel<<<P_POST / 8, 256, 0, stream>>>(
                hbuf, dinv4, rowinfo, csrsrc4, post, t1acc, hacc, s * N_NODES, s == 0);
        }
    }
    // accP = t1acc @ W2 + 4*b2 + hacc   — single bf16 MFMA GEMM (W2 snapshot-invariant)
    dim3 g1(H_DIM / 64, (P_POST + 63) / 64);
    gemm_l1_mfma<<<g1, 256, 0, stream>>>(t1acc, w2t, b2, hacc, accP, P_POST);

    classifier_kernel<<<P_POST / 8, 128, 0, stream>>>(accP, Wc1, bc1, Wc2, bc2, out);
}